// Round 19
// baseline (355.962 us; speedup 1.0000x reference)
//
#include <hip/hip_runtime.h>

// ---------------------------------------------------------------------------
// TextGraphSAGE: 2-layer SAGEConv (mean aggr), N=50000, D=768, H=128, C=4,
// E=800000.
//  - project BEFORE aggregating (mean commutes with linear map)
//  - CSR gather instead of scatter atomics (r1: 102M float atomics = 77%)
//  - r17 win: atomic-free slot-based fill; r18 win: r8 gemm engine (95us)
//  - r19: gemm C-epilogue 4-pass reusing As (LDS 26.6->9.2KB, restores
//    fill-block occupancy -- r18's +6us regression); sage1 widened to
//    16 edges in flight (4 lanes/edge x 4 uint4 = 2x outstanding loads,
//    half the shfl broadcasts).
// ---------------------------------------------------------------------------

typedef __bf16 bf16x8 __attribute__((ext_vector_type(8)));
typedef float  f32x4  __attribute__((ext_vector_type(4)));

__device__ __forceinline__ float bf16_lo(uint32_t w) {
    union { uint32_t u; float f; } c; c.u = w << 16; return c.f;
}
__device__ __forceinline__ float bf16_hi(uint32_t w) {
    union { uint32_t u; float f; } c; c.u = w & 0xffff0000u; return c.f;
}
__device__ __forceinline__ void acc8(float* a, uint4 w) {
    a[0] += bf16_lo(w.x); a[1] += bf16_hi(w.x);
    a[2] += bf16_lo(w.y); a[3] += bf16_hi(w.y);
    a[4] += bf16_lo(w.z); a[5] += bf16_hi(w.z);
    a[6] += bf16_lo(w.w); a[7] += bf16_hi(w.w);
}

// ---- prep: pack W into fragment-major bf16 Bp[kg][col][8] (kg=k/8, 96x256x8)
//      element (col,k) -> Bp[(k>>3)*2048 + col*8 + (k&7)]; also zero deg.
__global__ __launch_bounds__(256)
void prep(const float* __restrict__ W1l, const float* __restrict__ W1r,
          __bf16* __restrict__ Bp, int* __restrict__ deg, int N)
{
    int i = blockIdx.x * 256 + threadIdx.x;
    if (i < N) deg[i] = 0;
    if (i < 256 * 768) {
        int col = i / 768, k = i - col * 768;
        float v = (col < 128) ? W1l[col * 768 + k] : W1r[(col - 128) * 768 + k];
        Bp[((k >> 3) << 11) + (col << 3) + (k & 7)] = (__bf16)v;
    }
}

// ---- CSR build step 1: degree histogram + per-edge slot (atomic-free fill)
__global__ __launch_bounds__(256)
void csr_count(const int* __restrict__ ei, int* __restrict__ deg,
               int* __restrict__ slot, int E)
{
    int e = blockIdx.x * 256 + threadIdx.x;
    if (e >= E) return;
    slot[e] = atomicAdd(&deg[ei[E + e]], 1);
}

// ---- scan step 1: per-1024-block exclusive scan + block totals
__global__ __launch_bounds__(1024)
void scan1(const int* __restrict__ deg, int* __restrict__ row_ptr,
           int* __restrict__ partials, int N)
{
    __shared__ int buf[1024];
    int i = blockIdx.x * 1024 + threadIdx.x;
    int v = (i < N) ? deg[i] : 0;
    int val = v;
    buf[threadIdx.x] = val;
    __syncthreads();
    for (int off = 1; off < 1024; off <<= 1) {
        int t = (threadIdx.x >= (unsigned)off) ? buf[threadIdx.x - off] : 0;
        __syncthreads();
        val += t;
        buf[threadIdx.x] = val;
        __syncthreads();
    }
    if (i < N) row_ptr[i] = val - v;
    if (threadIdx.x == 1023) partials[blockIdx.x] = val;
}

// ---- scan steps 2+3 merged
__global__ __launch_bounds__(1024)
void scan23(int* __restrict__ row_ptr, const int* __restrict__ partials,
            int N, int E, int nb)
{
    __shared__ int soff;
    int b = blockIdx.x;
    if (threadIdx.x < 64) {
        int lane = threadIdx.x;
        int v = (lane < nb) ? partials[lane] : 0;
        int s = v;
        #pragma unroll
        for (int off = 1; off < 64; off <<= 1) {
            int t = __shfl_up(s, off);
            if (lane >= off) s += t;
        }
        if (lane == b) soff = s - v;
    }
    __syncthreads();
    int off = soff;
    int i = b * 1024 + threadIdx.x;
    if (i < N) row_ptr[i] += off;
    if (b == 0 && threadIdx.x == 0) row_ptr[N] = E;
}

// ---- fused: gemm tiles (blocks < gblocks) + csr_fill (blocks >= gblocks,
// atomic-free: pos = row_ptr[dst] + slot[e]).
// gemm: pq[M][256](bf16) = x[M][768](f32) @ W[256][768]^T.  r8 engine:
// 64x256 tile (A read ONCE), 512 threads (8 waves 2x4, wave-tile 32x64),
// BK=64. A: fp32 reg-prefetch -> cvt -> LDS. B: per-lane fragment loads
// from L2-resident packed Bp. C: 4-pass LDS-staged coalesced stores
// reusing As (total LDS 9.2KB -> 8 blocks/CU for fill blocks too).
__global__ __launch_bounds__(512)
void gemm_fill(const float* __restrict__ A, const __bf16* __restrict__ Bp,
               __bf16* __restrict__ Cb, int M, int gblocks,
               const int* __restrict__ ei, const int* __restrict__ row_ptr,
               const int* __restrict__ slot, int* __restrict__ csr_src, int E)
{
    constexpr int LDK = 72;                  // +8 bf16 pad (144B row stride)
    __shared__ __bf16 As[64][LDK];           // 9.2 KB (staging + C-stage)
    const int tid = threadIdx.x;

    if ((int)blockIdx.x >= gblocks) {
        // ------------- csr_fill: one edge per thread, NO atomics -------------
        int e = (blockIdx.x - gblocks) * 512 + tid;
        if (e < E) {
            int src = ei[e];
            int dst = ei[E + e];
            csr_src[row_ptr[dst] + slot[e]] = src;
        }
        return;
    }

    // ---------------- gemm path (r8 engine) ----------------
    const int bm   = blockIdx.x * 64;
    const int lane = tid & 63;
    const int wave = tid >> 6;               // 0..7
    const int wr = wave >> 2, wc = wave & 3; // wave tile: 32 rows x 64 cols
    const int l15 = lane & 15;
    const int lk  = lane >> 4;               // 0..3

    f32x4 acc[2][4] = {};
    float4 apref[2];

    const int arow = tid >> 3;               // 0..63
    const int akc  = (tid & 7) << 3;         // 0..56
    const __bf16* bbase = Bp + ((size_t)(wc * 64 + l15) << 3) + ((size_t)lk << 11);

    auto load_A = [&](int k0) {
        if (bm + arow < M) {
            const float* src = A + (size_t)(bm + arow) * 768 + k0 + akc;
            apref[0] = *(const float4*)src;
            apref[1] = *(const float4*)(src + 4);
        } else {
            apref[0] = make_float4(0.f, 0.f, 0.f, 0.f);
            apref[1] = make_float4(0.f, 0.f, 0.f, 0.f);
        }
    };

    load_A(0);
    for (int kt = 0; kt < 12; ++kt) {
        if (kt) __syncthreads();             // MFMA of kt-1 done with LDS
        {
            float4 f0 = apref[0], f1 = apref[1];
            bf16x8 b;
            b[0] = (__bf16)f0.x; b[1] = (__bf16)f0.y;
            b[2] = (__bf16)f0.z; b[3] = (__bf16)f0.w;
            b[4] = (__bf16)f1.x; b[5] = (__bf16)f1.y;
            b[6] = (__bf16)f1.z; b[7] = (__bf16)f1.w;
            *(bf16x8*)&As[arow][akc] = b;
        }
        __syncthreads();
        if (kt < 11) load_A((kt + 1) * 64);  // A burst in flight across MFMA

        bf16x8 bcur[2][4];
        #pragma unroll
        for (int ks = 0; ks < 2; ++ks)
            #pragma unroll
            for (int j = 0; j < 4; ++j)
                bcur[ks][j] = *(const bf16x8*)(bbase +
                    (((size_t)(kt * 8 + ks * 4) << 11) + ((size_t)j << 7)));

        #pragma unroll
        for (int ks = 0; ks < 2; ++ks) {
            int koff = ks * 32 + lk * 8;
            bf16x8 af[2];
            #pragma unroll
            for (int i = 0; i < 2; ++i)
                af[i] = *(const bf16x8*)&As[wr * 32 + i * 16 + l15][koff];
            #pragma unroll
            for (int i = 0; i < 2; ++i)
                #pragma unroll
                for (int j = 0; j < 4; ++j)
                    acc[i][j] = __builtin_amdgcn_mfma_f32_16x16x32_bf16(
                        af[i], bcur[ks][j], acc[i][j], 0, 0, 0);
        }
    }

    // ---- coalesced C epilogue: 4 passes of 64 cols reusing As.
    // C/D layout: col = lane&15, row = (lane>>4)*4 + reg  [m89-verified]
    #pragma unroll
    for (int qtr = 0; qtr < 4; ++qtr) {
        __syncthreads();                     // prev pass stores / MFMA done
        if (wc == qtr) {
            #pragma unroll
            for (int i = 0; i < 2; ++i)
                #pragma unroll
                for (int j = 0; j < 4; ++j)
                    #pragma unroll
                    for (int v = 0; v < 4; ++v)
                        As[wr * 32 + i * 16 + lk * 4 + v][j * 16 + l15] =
                            (__bf16)acc[i][j][v];
        }
        __syncthreads();
        // 64 rows x 64 cols = 512 x 16B chunks; 512 threads -> 1 each
        int row = tid >> 3, ch = tid & 7;
        if (bm + row < M)
            *(bf16x8*)(Cb + (size_t)(bm + row) * 256 + qtr * 64 + ch * 8) =
                *(const bf16x8*)&As[row][ch * 8];
    }
}

// ---- layer 1 + layer-2 projection, fused. One wave per node.
// 4 lanes per edge x 64B/lane (4 x uint4) -> 16 edges in flight / iteration.
// lane = g*4 + l: g = edge slot (0..15), l = feature quarter (32 feats).
__global__ __launch_bounds__(256)
void sage1_fused(const int* __restrict__ row_ptr, const int* __restrict__ csr_src,
                 const __bf16* __restrict__ pq, const float* __restrict__ b1,
                 const float* __restrict__ W2l, const float* __restrict__ W2r,
                 float* __restrict__ r, float* __restrict__ s, int N)
{
    __shared__ float Wl[512], Wr[512];
    for (int i = threadIdx.x; i < 512; i += 256) {
        Wl[i] = W2l[i];
        Wr[i] = W2r[i];
    }
    __syncthreads();

    int wid  = threadIdx.x >> 6;
    int lane = threadIdx.x & 63;
    int g = lane >> 2;          // edge slot 0..15
    int l = lane & 3;           // feature quarter 0..3
    int n = blockIdx.x * 4 + wid;
    if (n >= N) return;
    int beg = row_ptr[n], end = row_ptr[n + 1];

    float a[32] = {};           // feats l*32 + 0..31
    for (int eb = beg; eb < end; eb += 64) {
        int cnt = min(64, end - eb);
        int id = (eb + lane < end) ? csr_src[eb + lane] : 0;
        for (int t = 0; t < cnt; t += 16) {
            int src = __shfl(id, t + g);
            if (t + g < cnt) {
                const __bf16* row = pq + (size_t)src * 256 + l * 32;
                uint4 w0 = *(const uint4*)(row);
                uint4 w1 = *(const uint4*)(row + 8);
                uint4 w2 = *(const uint4*)(row + 16);
                uint4 w3 = *(const uint4*)(row + 24);
                acc8(a, w0); acc8(a + 8, w1); acc8(a + 16, w2); acc8(a + 24, w3);
            }
        }
    }
    // fold edge-slot partials (g varies over lane bits 2..5)
    #pragma unroll
    for (int off = 4; off <= 32; off <<= 1)
        #pragma unroll
        for (int c = 0; c < 32; ++c)
            a[c] += __shfl_xor(a[c], off);

    float inv = 1.0f / fmaxf((float)(end - beg), 1.0f);
    const __bf16* qrow = pq + (size_t)n * 256 + 128 + l * 32;
    uint4 qw[4];
    qw[0] = *(const uint4*)(qrow);
    qw[1] = *(const uint4*)(qrow + 8);
    qw[2] = *(const uint4*)(qrow + 16);
    qw[3] = *(const uint4*)(qrow + 24);
    float h[32];
    #pragma unroll
    for (int b = 0; b < 4; ++b) {
        const uint32_t* wp = (const uint32_t*)&qw[b];
        #pragma unroll
        for (int p = 0; p < 4; ++p) {
            int c = b * 8 + p * 2;
            h[c]     = fmaxf(a[c]     * inv + b1[l * 32 + c]     + bf16_lo(wp[p]), 0.f);
            h[c + 1] = fmaxf(a[c + 1] * inv + b1[l * 32 + c + 1] + bf16_hi(wp[p]), 0.f);
        }
    }

    // proj2 inline: lane dots its 32 feats; reduce across the 4 l-values
    float part[8];
    #pragma unroll
    for (int cc = 0; cc < 4; ++cc) {
        float pl = 0.f, pr = 0.f;
        #pragma unroll
        for (int c = 0; c < 32; ++c) {
            pl = fmaf(h[c], Wl[cc * 128 + l * 32 + c], pl);
            pr = fmaf(h[c], Wr[cc * 128 + l * 32 + c], pr);
        }
        part[cc] = pl; part[4 + cc] = pr;
    }
    #pragma unroll
    for (int off = 1; off <= 2; off <<= 1)
        #pragma unroll
        for (int c = 0; c < 8; ++c)
            part[c] += __shfl_xor(part[c], off);
    if (lane == 0) {
        *(float4*)(r + (size_t)n * 4) = make_float4(part[0], part[1], part[2], part[3]);
        *(float4*)(s + (size_t)n * 4) = make_float4(part[4], part[5], part[6], part[7]);
    }
}

// ---- layer 2: out[n] = mean_{src} r[src] + b2 + s[n]
__global__ __launch_bounds__(256)
void sage2_gather(const int* __restrict__ row_ptr, const int* __restrict__ csr_src,
                  const float* __restrict__ r, const float* __restrict__ s,
                  const float* __restrict__ b2, float* __restrict__ out, int N)
{
    int t = blockIdx.x * 256 + threadIdx.x;
    if (t >= N * 4) return;
    int n = t >> 2, c = t & 3;
    int beg = row_ptr[n], end = row_ptr[n + 1];
    float acc = 0.f;
    for (int e = beg; e < end; ++e)
        acc += r[(size_t)csr_src[e] * 4 + c];
    out[t] = acc / fmaxf((float)(end - beg), 1.0f) + b2[c] + s[t];
}

extern "C" void kernel_launch(void* const* d_in, const int* in_sizes, int n_in,
                              void* d_out, int out_size, void* d_ws, size_t ws_size,
                              hipStream_t stream)
{
    const float* x   = (const float*)d_in[0];
    const int*   ei  = (const int*)d_in[1];
    const float* W1l = (const float*)d_in[2];
    const float* b1l = (const float*)d_in[3];
    const float* W1r = (const float*)d_in[4];
    const float* W2l = (const float*)d_in[5];
    const float* b2l = (const float*)d_in[6];
    const float* W2r = (const float*)d_in[7];
    float* out = (float*)d_out;

    const int N = in_sizes[0] / 768;   // 50000
    const int E = in_sizes[1] / 2;     // 800000
    const int NB = (N + 1023) / 1024;  // 49 scan blocks
    const int gblocks = (N + 63) / 64;   // 782 gemm tiles (BN=256 full width)
    const int fblocks = (E + 511) / 512; // 1563 fill blocks, 1 edge/thread

    char* ws = (char*)d_ws;
    size_t off = 0;
    auto alloc = [&](size_t bytes) -> void* {
        void* pp = ws + off;
        off += (bytes + 255) & ~(size_t)255;
        return pp;
    };
    __bf16* pq      = (__bf16*)alloc((size_t)N * 256 * 2);
    float*  r       = (float*)alloc((size_t)N * 4 * 4);
    float*  s       = (float*)alloc((size_t)N * 4 * 4);
    __bf16* Bp      = (__bf16*)alloc((size_t)256 * 768 * 2);
    int*    deg     = (int*)alloc((size_t)N * 4);
    int*    row_ptr = (int*)alloc((size_t)(N + 1) * 4);
    int*    slot    = (int*)alloc((size_t)E * 4);
    int*    csr_src = (int*)alloc((size_t)E * 4);
    int*    partials= (int*)alloc((size_t)64 * 4);

    // ---- pack W fragment-major bf16 + zero deg
    prep<<<(256 * 768 + 255) / 256, 256, 0, stream>>>(W1l, W1r, Bp, deg, N);

    // ---- CSR: count (+slot) + scans (fill happens inside gemm_fill)
    csr_count<<<(E + 255) / 256, 256, 0, stream>>>(ei, deg, slot, E);
    scan1<<<NB, 1024, 0, stream>>>(deg, row_ptr, partials, N);
    scan23<<<NB, 1024, 0, stream>>>(row_ptr, partials, N, E, NB);

    // ---- fused layer-1 projection (r8 engine + 4-pass C) + csr_fill
    gemm_fill<<<gblocks + fblocks, 512, 0, stream>>>(x, Bp, pq, N, gblocks,
                                                     ei, row_ptr, slot,
                                                     csr_src, E);

    // ---- layer 1 aggregate + epilogue + layer-2 projection (fused)
    sage1_fused<<<(N + 3) / 4, 256, 0, stream>>>(row_ptr, csr_src, pq, b1l,
                                                 W2l, W2r, r, s, N);

    // ---- layer 2 aggregate + epilogue
    sage2_gather<<<(N * 4 + 255) / 256, 256, 0, stream>>>(row_ptr, csr_src, r, s, b2l, out, N);
}

// Round 20
// 190.290 us; speedup vs baseline: 1.8706x; 1.8706x over previous
//
#include <hip/hip_runtime.h>

// ---------------------------------------------------------------------------
// TextGraphSAGE: 2-layer SAGEConv (mean aggr), N=50000, D=768, H=128, C=4,
// E=800000.
//  - project BEFORE aggregating (mean commutes with linear map)
//  - CSR gather instead of scatter atomics (r1: 102M float atomics = 77%)
//  - r17 win: atomic-free slot-based fill; r18 win: r8 gemm engine
//  - r19 lesson: 16-edge sage1 = 128 shfl/node (ds_bpermute -> 7.2e7 LDS
//    conflicts, 244us). r20: sage1 reverted to the proven 8-edge form;
//    gemm keeps the 4-pass C epilogue (9.2KB LDS, mildly positive).
// ---------------------------------------------------------------------------

typedef __bf16 bf16x8 __attribute__((ext_vector_type(8)));
typedef float  f32x4  __attribute__((ext_vector_type(4)));

__device__ __forceinline__ float bf16_lo(uint32_t w) {
    union { uint32_t u; float f; } c; c.u = w << 16; return c.f;
}
__device__ __forceinline__ float bf16_hi(uint32_t w) {
    union { uint32_t u; float f; } c; c.u = w & 0xffff0000u; return c.f;
}

// ---- prep: pack W into fragment-major bf16 Bp[kg][col][8] (kg=k/8, 96x256x8)
//      element (col,k) -> Bp[(k>>3)*2048 + col*8 + (k&7)]; also zero deg.
__global__ __launch_bounds__(256)
void prep(const float* __restrict__ W1l, const float* __restrict__ W1r,
          __bf16* __restrict__ Bp, int* __restrict__ deg, int N)
{
    int i = blockIdx.x * 256 + threadIdx.x;
    if (i < N) deg[i] = 0;
    if (i < 256 * 768) {
        int col = i / 768, k = i - col * 768;
        float v = (col < 128) ? W1l[col * 768 + k] : W1r[(col - 128) * 768 + k];
        Bp[((k >> 3) << 11) + (col << 3) + (k & 7)] = (__bf16)v;
    }
}

// ---- CSR build step 1: degree histogram + per-edge slot (atomic-free fill)
__global__ __launch_bounds__(256)
void csr_count(const int* __restrict__ ei, int* __restrict__ deg,
               int* __restrict__ slot, int E)
{
    int e = blockIdx.x * 256 + threadIdx.x;
    if (e >= E) return;
    slot[e] = atomicAdd(&deg[ei[E + e]], 1);
}

// ---- scan step 1: per-1024-block exclusive scan + block totals
__global__ __launch_bounds__(1024)
void scan1(const int* __restrict__ deg, int* __restrict__ row_ptr,
           int* __restrict__ partials, int N)
{
    __shared__ int buf[1024];
    int i = blockIdx.x * 1024 + threadIdx.x;
    int v = (i < N) ? deg[i] : 0;
    int val = v;
    buf[threadIdx.x] = val;
    __syncthreads();
    for (int off = 1; off < 1024; off <<= 1) {
        int t = (threadIdx.x >= (unsigned)off) ? buf[threadIdx.x - off] : 0;
        __syncthreads();
        val += t;
        buf[threadIdx.x] = val;
        __syncthreads();
    }
    if (i < N) row_ptr[i] = val - v;
    if (threadIdx.x == 1023) partials[blockIdx.x] = val;
}

// ---- scan steps 2+3 merged
__global__ __launch_bounds__(1024)
void scan23(int* __restrict__ row_ptr, const int* __restrict__ partials,
            int N, int E, int nb)
{
    __shared__ int soff;
    int b = blockIdx.x;
    if (threadIdx.x < 64) {
        int lane = threadIdx.x;
        int v = (lane < nb) ? partials[lane] : 0;
        int s = v;
        #pragma unroll
        for (int off = 1; off < 64; off <<= 1) {
            int t = __shfl_up(s, off);
            if (lane >= off) s += t;
        }
        if (lane == b) soff = s - v;
    }
    __syncthreads();
    int off = soff;
    int i = b * 1024 + threadIdx.x;
    if (i < N) row_ptr[i] += off;
    if (b == 0 && threadIdx.x == 0) row_ptr[N] = E;
}

// ---- fused: gemm tiles (blocks < gblocks) + csr_fill (blocks >= gblocks,
// atomic-free: pos = row_ptr[dst] + slot[e]).
// gemm: pq[M][256](bf16) = x[M][768](f32) @ W[256][768]^T.  r8 engine:
// 64x256 tile (A read ONCE), 512 threads (8 waves 2x4, wave-tile 32x64),
// BK=64. A: fp32 reg-prefetch -> cvt -> LDS. B: per-lane fragment loads
// from L2-resident packed Bp. C: 4-pass LDS-staged coalesced stores
// reusing As (total LDS 9.2KB).
__global__ __launch_bounds__(512)
void gemm_fill(const float* __restrict__ A, const __bf16* __restrict__ Bp,
               __bf16* __restrict__ Cb, int M, int gblocks,
               const int* __restrict__ ei, const int* __restrict__ row_ptr,
               const int* __restrict__ slot, int* __restrict__ csr_src, int E)
{
    constexpr int LDK = 72;                  // +8 bf16 pad (144B row stride)
    __shared__ __bf16 As[64][LDK];           // 9.2 KB (staging + C-stage)
    const int tid = threadIdx.x;

    if ((int)blockIdx.x >= gblocks) {
        // ------------- csr_fill: one edge per thread, NO atomics -------------
        int e = (blockIdx.x - gblocks) * 512 + tid;
        if (e < E) {
            int src = ei[e];
            int dst = ei[E + e];
            csr_src[row_ptr[dst] + slot[e]] = src;
        }
        return;
    }

    // ---------------- gemm path (r8 engine) ----------------
    const int bm   = blockIdx.x * 64;
    const int lane = tid & 63;
    const int wave = tid >> 6;               // 0..7
    const int wr = wave >> 2, wc = wave & 3; // wave tile: 32 rows x 64 cols
    const int l15 = lane & 15;
    const int lk  = lane >> 4;               // 0..3

    f32x4 acc[2][4] = {};
    float4 apref[2];

    const int arow = tid >> 3;               // 0..63
    const int akc  = (tid & 7) << 3;         // 0..56
    const __bf16* bbase = Bp + ((size_t)(wc * 64 + l15) << 3) + ((size_t)lk << 11);

    auto load_A = [&](int k0) {
        if (bm + arow < M) {
            const float* src = A + (size_t)(bm + arow) * 768 + k0 + akc;
            apref[0] = *(const float4*)src;
            apref[1] = *(const float4*)(src + 4);
        } else {
            apref[0] = make_float4(0.f, 0.f, 0.f, 0.f);
            apref[1] = make_float4(0.f, 0.f, 0.f, 0.f);
        }
    };

    load_A(0);
    for (int kt = 0; kt < 12; ++kt) {
        if (kt) __syncthreads();             // MFMA of kt-1 done with LDS
        {
            float4 f0 = apref[0], f1 = apref[1];
            bf16x8 b;
            b[0] = (__bf16)f0.x; b[1] = (__bf16)f0.y;
            b[2] = (__bf16)f0.z; b[3] = (__bf16)f0.w;
            b[4] = (__bf16)f1.x; b[5] = (__bf16)f1.y;
            b[6] = (__bf16)f1.z; b[7] = (__bf16)f1.w;
            *(bf16x8*)&As[arow][akc] = b;
        }
        __syncthreads();
        if (kt < 11) load_A((kt + 1) * 64);  // A burst in flight across MFMA

        bf16x8 bcur[2][4];
        #pragma unroll
        for (int ks = 0; ks < 2; ++ks)
            #pragma unroll
            for (int j = 0; j < 4; ++j)
                bcur[ks][j] = *(const bf16x8*)(bbase +
                    (((size_t)(kt * 8 + ks * 4) << 11) + ((size_t)j << 7)));

        #pragma unroll
        for (int ks = 0; ks < 2; ++ks) {
            int koff = ks * 32 + lk * 8;
            bf16x8 af[2];
            #pragma unroll
            for (int i = 0; i < 2; ++i)
                af[i] = *(const bf16x8*)&As[wr * 32 + i * 16 + l15][koff];
            #pragma unroll
            for (int i = 0; i < 2; ++i)
                #pragma unroll
                for (int j = 0; j < 4; ++j)
                    acc[i][j] = __builtin_amdgcn_mfma_f32_16x16x32_bf16(
                        af[i], bcur[ks][j], acc[i][j], 0, 0, 0);
        }
    }

    // ---- coalesced C epilogue: 4 passes of 64 cols reusing As.
    // C/D layout: col = lane&15, row = (lane>>4)*4 + reg  [m89-verified]
    #pragma unroll
    for (int qtr = 0; qtr < 4; ++qtr) {
        __syncthreads();                     // prev pass stores / MFMA done
        if (wc == qtr) {
            #pragma unroll
            for (int i = 0; i < 2; ++i)
                #pragma unroll
                for (int j = 0; j < 4; ++j)
                    #pragma unroll
                    for (int v = 0; v < 4; ++v)
                        As[wr * 32 + i * 16 + lk * 4 + v][j * 16 + l15] =
                            (__bf16)acc[i][j][v];
        }
        __syncthreads();
        int row = tid >> 3, ch = tid & 7;
        if (bm + row < M)
            *(bf16x8*)(Cb + (size_t)(bm + row) * 256 + qtr * 64 + ch * 8) =
                *(const bf16x8*)&As[row][ch * 8];
    }
}

// ---- layer 1 + layer-2 projection, fused. One wave per node.
// 8 lanes per edge x 32B/lane (2 x uint4) -> 8 edges in flight / iteration.
// (r18-proven form; r19's 16-edge variant regressed via shfl storm)
__global__ __launch_bounds__(256)
void sage1_fused(const int* __restrict__ row_ptr, const int* __restrict__ csr_src,
                 const __bf16* __restrict__ pq, const float* __restrict__ b1,
                 const float* __restrict__ W2l, const float* __restrict__ W2r,
                 float* __restrict__ r, float* __restrict__ s, int N)
{
    __shared__ float Wl[512], Wr[512];
    for (int i = threadIdx.x; i < 512; i += 256) {
        Wl[i] = W2l[i];
        Wr[i] = W2r[i];
    }
    __syncthreads();

    int wid  = threadIdx.x >> 6;
    int lane = threadIdx.x & 63;
    int g = lane >> 3;          // edge slot 0..7
    int l = lane & 7;           // feature block 0..7
    int n = blockIdx.x * 4 + wid;
    if (n >= N) return;
    int beg = row_ptr[n], end = row_ptr[n + 1];

    float a0[8] = {}, a1[8] = {};   // feats l*8+j and 64+l*8+j
    for (int eb = beg; eb < end; eb += 64) {
        int cnt = min(64, end - eb);
        int id = (eb + lane < end) ? csr_src[eb + lane] : 0;
        for (int t = 0; t < cnt; t += 8) {
            int src = __shfl(id, t + g);
            if (t + g < cnt) {
                const __bf16* row = pq + (size_t)src * 256;
                uint4 w0 = *(const uint4*)(row + l * 8);
                uint4 w1 = *(const uint4*)(row + 64 + l * 8);
                a0[0] += bf16_lo(w0.x); a0[1] += bf16_hi(w0.x);
                a0[2] += bf16_lo(w0.y); a0[3] += bf16_hi(w0.y);
                a0[4] += bf16_lo(w0.z); a0[5] += bf16_hi(w0.z);
                a0[6] += bf16_lo(w0.w); a0[7] += bf16_hi(w0.w);
                a1[0] += bf16_lo(w1.x); a1[1] += bf16_hi(w1.x);
                a1[2] += bf16_lo(w1.y); a1[3] += bf16_hi(w1.y);
                a1[4] += bf16_lo(w1.z); a1[5] += bf16_hi(w1.z);
                a1[6] += bf16_lo(w1.w); a1[7] += bf16_hi(w1.w);
            }
        }
    }
    #pragma unroll
    for (int c = 0; c < 8; ++c) {
        a0[c] += __shfl_xor(a0[c], 8);  a1[c] += __shfl_xor(a1[c], 8);
        a0[c] += __shfl_xor(a0[c], 16); a1[c] += __shfl_xor(a1[c], 16);
        a0[c] += __shfl_xor(a0[c], 32); a1[c] += __shfl_xor(a1[c], 32);
    }

    float inv = 1.0f / fmaxf((float)(end - beg), 1.0f);
    const __bf16* qrow = pq + (size_t)n * 256 + 128;
    uint4  qw0 = *(const uint4*)(qrow + l * 8);
    uint4  qw1 = *(const uint4*)(qrow + 64 + l * 8);
    float4 bv00 = *(const float4*)(b1 + l * 8);
    float4 bv01 = *(const float4*)(b1 + l * 8 + 4);
    float4 bv10 = *(const float4*)(b1 + 64 + l * 8);
    float4 bv11 = *(const float4*)(b1 + 64 + l * 8 + 4);
    float h0[8], h1[8];
    h0[0] = fmaxf(a0[0] * inv + bv00.x + bf16_lo(qw0.x), 0.f);
    h0[1] = fmaxf(a0[1] * inv + bv00.y + bf16_hi(qw0.x), 0.f);
    h0[2] = fmaxf(a0[2] * inv + bv00.z + bf16_lo(qw0.y), 0.f);
    h0[3] = fmaxf(a0[3] * inv + bv00.w + bf16_hi(qw0.y), 0.f);
    h0[4] = fmaxf(a0[4] * inv + bv01.x + bf16_lo(qw0.z), 0.f);
    h0[5] = fmaxf(a0[5] * inv + bv01.y + bf16_hi(qw0.z), 0.f);
    h0[6] = fmaxf(a0[6] * inv + bv01.z + bf16_lo(qw0.w), 0.f);
    h0[7] = fmaxf(a0[7] * inv + bv01.w + bf16_hi(qw0.w), 0.f);
    h1[0] = fmaxf(a1[0] * inv + bv10.x + bf16_lo(qw1.x), 0.f);
    h1[1] = fmaxf(a1[1] * inv + bv10.y + bf16_hi(qw1.x), 0.f);
    h1[2] = fmaxf(a1[2] * inv + bv10.z + bf16_lo(qw1.y), 0.f);
    h1[3] = fmaxf(a1[3] * inv + bv10.w + bf16_hi(qw1.y), 0.f);
    h1[4] = fmaxf(a1[4] * inv + bv11.x + bf16_lo(qw1.z), 0.f);
    h1[5] = fmaxf(a1[5] * inv + bv11.y + bf16_hi(qw1.z), 0.f);
    h1[6] = fmaxf(a1[6] * inv + bv11.z + bf16_lo(qw1.w), 0.f);
    h1[7] = fmaxf(a1[7] * inv + bv11.w + bf16_hi(qw1.w), 0.f);

    float part[8];
    #pragma unroll
    for (int c = 0; c < 4; ++c) {
        float pl = 0.f, pr = 0.f;
        #pragma unroll
        for (int j = 0; j < 8; ++j) {
            pl = fmaf(h0[j], Wl[c * 128 + l * 8 + j], pl);
            pl = fmaf(h1[j], Wl[c * 128 + 64 + l * 8 + j], pl);
            pr = fmaf(h0[j], Wr[c * 128 + l * 8 + j], pr);
            pr = fmaf(h1[j], Wr[c * 128 + 64 + l * 8 + j], pr);
        }
        part[c] = pl; part[4 + c] = pr;
    }
    #pragma unroll
    for (int off = 4; off; off >>= 1)
        #pragma unroll
        for (int c = 0; c < 8; ++c)
            part[c] += __shfl_xor(part[c], off);
    if (lane == 0) {
        *(float4*)(r + (size_t)n * 4) = make_float4(part[0], part[1], part[2], part[3]);
        *(float4*)(s + (size_t)n * 4) = make_float4(part[4], part[5], part[6], part[7]);
    }
}

// ---- layer 2: out[n] = mean_{src} r[src] + b2 + s[n]
__global__ __launch_bounds__(256)
void sage2_gather(const int* __restrict__ row_ptr, const int* __restrict__ csr_src,
                  const float* __restrict__ r, const float* __restrict__ s,
                  const float* __restrict__ b2, float* __restrict__ out, int N)
{
    int t = blockIdx.x * 256 + threadIdx.x;
    if (t >= N * 4) return;
    int n = t >> 2, c = t & 3;
    int beg = row_ptr[n], end = row_ptr[n + 1];
    float acc = 0.f;
    for (int e = beg; e < end; ++e)
        acc += r[(size_t)csr_src[e] * 4 + c];
    out[t] = acc / fmaxf((float)(end - beg), 1.0f) + b2[c] + s[t];
}

extern "C" void kernel_launch(void* const* d_in, const int* in_sizes, int n_in,
                              void* d_out, int out_size, void* d_ws, size_t ws_size,
                              hipStream_t stream)
{
    const float* x   = (const float*)d_in[0];
    const int*   ei  = (const int*)d_in[1];
    const float* W1l = (const float*)d_in[2];
    const float* b1l = (const float*)d_in[3];
    const float* W1r = (const float*)d_in[4];
    const float* W2l = (const float*)d_in[5];
    const float* b2l = (const float*)d_in[6];
    const float* W2r = (const float*)d_in[7];
    float* out = (float*)d_out;

    const int N = in_sizes[0] / 768;   // 50000
    const int E = in_sizes[1] / 2;     // 800000
    const int NB = (N + 1023) / 1024;  // 49 scan blocks
    const int gblocks = (N + 63) / 64;   // 782 gemm tiles (BN=256 full width)
    const int fblocks = (E + 511) / 512; // 1563 fill blocks, 1 edge/thread

    char* ws = (char*)d_ws;
    size_t off = 0;
    auto alloc = [&](size_t bytes) -> void* {
        void* pp = ws + off;
        off += (bytes + 255) & ~(size_t)255;
        return pp;
    };
    __bf16* pq      = (__bf16*)alloc((size_t)N * 256 * 2);
    float*  r       = (float*)alloc((size_t)N * 4 * 4);
    float*  s       = (float*)alloc((size_t)N * 4 * 4);
    __bf16* Bp      = (__bf16*)alloc((size_t)256 * 768 * 2);
    int*    deg     = (int*)alloc((size_t)N * 4);
    int*    row_ptr = (int*)alloc((size_t)(N + 1) * 4);
    int*    slot    = (int*)alloc((size_t)E * 4);
    int*    csr_src = (int*)alloc((size_t)E * 4);
    int*    partials= (int*)alloc((size_t)64 * 4);

    // ---- pack W fragment-major bf16 + zero deg
    prep<<<(256 * 768 + 255) / 256, 256, 0, stream>>>(W1l, W1r, Bp, deg, N);

    // ---- CSR: count (+slot) + scans (fill happens inside gemm_fill)
    csr_count<<<(E + 255) / 256, 256, 0, stream>>>(ei, deg, slot, E);
    scan1<<<NB, 1024, 0, stream>>>(deg, row_ptr, partials, N);
    scan23<<<NB, 1024, 0, stream>>>(row_ptr, partials, N, E, NB);

    // ---- fused layer-1 projection (r8 engine + 4-pass C) + csr_fill
    gemm_fill<<<gblocks + fblocks, 512, 0, stream>>>(x, Bp, pq, N, gblocks,
                                                     ei, row_ptr, slot,
                                                     csr_src, E);

    // ---- layer 1 aggregate + epilogue + layer-2 projection (fused)
    sage1_fused<<<(N + 3) / 4, 256, 0, stream>>>(row_ptr, csr_src, pq, b1l,
                                                 W2l, W2r, r, s, N);

    // ---- layer 2 aggregate + epilogue
    sage2_gather<<<(N * 4 + 255) / 256, 256, 0, stream>>>(row_ptr, csr_src, r, s, b2l, out, N);
}

// Round 21
// 186.248 us; speedup vs baseline: 1.9112x; 1.0217x over previous
//
#include <hip/hip_runtime.h>

// ---------------------------------------------------------------------------
// TextGraphSAGE: 2-layer SAGEConv (mean aggr), N=50000, D=768, H=128, C=4,
// E=800000.
//  - project BEFORE aggregating (mean commutes with linear map)
//  - CSR gather instead of scatter atomics (r1: 102M float atomics = 77%)
//  - r17 win: atomic-free slot-based fill; r18 win: r8 gemm engine
//  - r19 lesson: wide shuffle-folds = LDS conflict storm (reverted)
//  - r21: fill blocks FIRST in the fused dispatch (r20's 1300-block lonely
//    fill tail after the 4-blocks/CU-capped gemm wave was the ~7us r17->r20
//    regression); gemm gets 2-deep A prefetch (tile kt+2 in flight).
// ---------------------------------------------------------------------------

typedef __bf16 bf16x8 __attribute__((ext_vector_type(8)));
typedef float  f32x4  __attribute__((ext_vector_type(4)));

__device__ __forceinline__ float bf16_lo(uint32_t w) {
    union { uint32_t u; float f; } c; c.u = w << 16; return c.f;
}
__device__ __forceinline__ float bf16_hi(uint32_t w) {
    union { uint32_t u; float f; } c; c.u = w & 0xffff0000u; return c.f;
}

// ---- prep: pack W into fragment-major bf16 Bp[kg][col][8] (kg=k/8, 96x256x8)
//      element (col,k) -> Bp[(k>>3)*2048 + col*8 + (k&7)]; also zero deg.
__global__ __launch_bounds__(256)
void prep(const float* __restrict__ W1l, const float* __restrict__ W1r,
          __bf16* __restrict__ Bp, int* __restrict__ deg, int N)
{
    int i = blockIdx.x * 256 + threadIdx.x;
    if (i < N) deg[i] = 0;
    if (i < 256 * 768) {
        int col = i / 768, k = i - col * 768;
        float v = (col < 128) ? W1l[col * 768 + k] : W1r[(col - 128) * 768 + k];
        Bp[((k >> 3) << 11) + (col << 3) + (k & 7)] = (__bf16)v;
    }
}

// ---- CSR build step 1: degree histogram + per-edge slot (atomic-free fill)
__global__ __launch_bounds__(256)
void csr_count(const int* __restrict__ ei, int* __restrict__ deg,
               int* __restrict__ slot, int E)
{
    int e = blockIdx.x * 256 + threadIdx.x;
    if (e >= E) return;
    slot[e] = atomicAdd(&deg[ei[E + e]], 1);
}

// ---- scan step 1: per-1024-block exclusive scan + block totals
__global__ __launch_bounds__(1024)
void scan1(const int* __restrict__ deg, int* __restrict__ row_ptr,
           int* __restrict__ partials, int N)
{
    __shared__ int buf[1024];
    int i = blockIdx.x * 1024 + threadIdx.x;
    int v = (i < N) ? deg[i] : 0;
    int val = v;
    buf[threadIdx.x] = val;
    __syncthreads();
    for (int off = 1; off < 1024; off <<= 1) {
        int t = (threadIdx.x >= (unsigned)off) ? buf[threadIdx.x - off] : 0;
        __syncthreads();
        val += t;
        buf[threadIdx.x] = val;
        __syncthreads();
    }
    if (i < N) row_ptr[i] = val - v;
    if (threadIdx.x == 1023) partials[blockIdx.x] = val;
}

// ---- scan steps 2+3 merged
__global__ __launch_bounds__(1024)
void scan23(int* __restrict__ row_ptr, const int* __restrict__ partials,
            int N, int E, int nb)
{
    __shared__ int soff;
    int b = blockIdx.x;
    if (threadIdx.x < 64) {
        int lane = threadIdx.x;
        int v = (lane < nb) ? partials[lane] : 0;
        int s = v;
        #pragma unroll
        for (int off = 1; off < 64; off <<= 1) {
            int t = __shfl_up(s, off);
            if (lane >= off) s += t;
        }
        if (lane == b) soff = s - v;
    }
    __syncthreads();
    int off = soff;
    int i = b * 1024 + threadIdx.x;
    if (i < N) row_ptr[i] += off;
    if (b == 0 && threadIdx.x == 0) row_ptr[N] = E;
}

// ---- fused: csr_fill (blocks < fblocks, atomic-free, retire fast) then
// gemm tiles (blocks >= fblocks).
// gemm: pq[M][256](bf16) = x[M][768](f32) @ W[256][768]^T.  r8 engine:
// 64x256 tile (A read ONCE), 512 threads (8 waves 2x4, wave-tile 32x64),
// BK=64, 2-deep A prefetch. B: per-lane fragment loads from L2-resident
// packed Bp. C: 4-pass LDS-staged coalesced stores reusing As (9.2KB LDS).
__global__ __launch_bounds__(512)
void gemm_fill(const float* __restrict__ A, const __bf16* __restrict__ Bp,
               __bf16* __restrict__ Cb, int M, int fblocks,
               const int* __restrict__ ei, const int* __restrict__ row_ptr,
               const int* __restrict__ slot, int* __restrict__ csr_src, int E)
{
    constexpr int LDK = 72;                  // +8 bf16 pad (144B row stride)
    __shared__ __bf16 As[64][LDK];           // 9.2 KB (staging + C-stage)
    const int tid = threadIdx.x;

    if ((int)blockIdx.x < fblocks) {
        // ------------- csr_fill: one edge per thread, NO atomics -------------
        int e = blockIdx.x * 512 + tid;
        if (e < E) {
            int src = ei[e];
            int dst = ei[E + e];
            csr_src[row_ptr[dst] + slot[e]] = src;
        }
        return;
    }

    // ---------------- gemm path (r8 engine, 2-deep prefetch) ----------------
    const int bm   = (blockIdx.x - fblocks) * 64;
    const int lane = tid & 63;
    const int wave = tid >> 6;               // 0..7
    const int wr = wave >> 2, wc = wave & 3; // wave tile: 32 rows x 64 cols
    const int l15 = lane & 15;
    const int lk  = lane >> 4;               // 0..3

    f32x4 acc[2][4] = {};

    const int arow = tid >> 3;               // 0..63
    const int akc  = (tid & 7) << 3;         // 0..56
    const __bf16* bbase = Bp + ((size_t)(wc * 64 + l15) << 3) + ((size_t)lk << 11);
    const float* asrc = A + (size_t)min(bm + arow, M - 1) * 768 + akc;
    const bool arow_ok = (bm + arow < M);    // else duplicate row M-1 (unstored)

    float4 pA0, pA1, pB0, pB1;               // pA = tile kt, pB = tile kt+1
    pA0 = *(const float4*)(asrc);
    pA1 = *(const float4*)(asrc + 4);
    pB0 = *(const float4*)(asrc + 64);
    pB1 = *(const float4*)(asrc + 68);
    if (!arow_ok) { pA0 = pA1 = pB0 = pB1 = make_float4(0.f, 0.f, 0.f, 0.f); }

    for (int kt = 0; kt < 12; ++kt) {
        if (kt) __syncthreads();             // MFMA of kt-1 done with LDS
        {
            bf16x8 b;
            b[0] = (__bf16)pA0.x; b[1] = (__bf16)pA0.y;
            b[2] = (__bf16)pA0.z; b[3] = (__bf16)pA0.w;
            b[4] = (__bf16)pA1.x; b[5] = (__bf16)pA1.y;
            b[6] = (__bf16)pA1.z; b[7] = (__bf16)pA1.w;
            *(bf16x8*)&As[arow][akc] = b;
        }
        __syncthreads();
        // shift pipeline: pA <- pB; issue load of tile kt+2 into pB
        pA0 = pB0; pA1 = pB1;
        if (kt < 10) {
            if (arow_ok) {
                pB0 = *(const float4*)(asrc + (kt + 2) * 64);
                pB1 = *(const float4*)(asrc + (kt + 2) * 64 + 4);
            }
        }

        bf16x8 bcur[2][4];
        #pragma unroll
        for (int ks = 0; ks < 2; ++ks)
            #pragma unroll
            for (int j = 0; j < 4; ++j)
                bcur[ks][j] = *(const bf16x8*)(bbase +
                    (((size_t)(kt * 8 + ks * 4) << 11) + ((size_t)j << 7)));

        #pragma unroll
        for (int ks = 0; ks < 2; ++ks) {
            int koff = ks * 32 + lk * 8;
            bf16x8 af[2];
            #pragma unroll
            for (int i = 0; i < 2; ++i)
                af[i] = *(const bf16x8*)&As[wr * 32 + i * 16 + l15][koff];
            #pragma unroll
            for (int i = 0; i < 2; ++i)
                #pragma unroll
                for (int j = 0; j < 4; ++j)
                    acc[i][j] = __builtin_amdgcn_mfma_f32_16x16x32_bf16(
                        af[i], bcur[ks][j], acc[i][j], 0, 0, 0);
        }
    }

    // ---- coalesced C epilogue: 4 passes of 64 cols reusing As.
    // C/D layout: col = lane&15, row = (lane>>4)*4 + reg  [m89-verified]
    #pragma unroll
    for (int qtr = 0; qtr < 4; ++qtr) {
        __syncthreads();                     // prev pass stores / MFMA done
        if (wc == qtr) {
            #pragma unroll
            for (int i = 0; i < 2; ++i)
                #pragma unroll
                for (int j = 0; j < 4; ++j)
                    #pragma unroll
                    for (int v = 0; v < 4; ++v)
                        As[wr * 32 + i * 16 + lk * 4 + v][j * 16 + l15] =
                            (__bf16)acc[i][j][v];
        }
        __syncthreads();
        int row = tid >> 3, ch = tid & 7;
        if (bm + row < M)
            *(bf16x8*)(Cb + (size_t)(bm + row) * 256 + qtr * 64 + ch * 8) =
                *(const bf16x8*)&As[row][ch * 8];
    }
}

// ---- layer 1 + layer-2 projection, fused. One wave per node.
// 8 lanes per edge x 32B/lane (2 x uint4) -> 8 edges in flight / iteration.
__global__ __launch_bounds__(256)
void sage1_fused(const int* __restrict__ row_ptr, const int* __restrict__ csr_src,
                 const __bf16* __restrict__ pq, const float* __restrict__ b1,
                 const float* __restrict__ W2l, const float* __restrict__ W2r,
                 float* __restrict__ r, float* __restrict__ s, int N)
{
    __shared__ float Wl[512], Wr[512];
    for (int i = threadIdx.x; i < 512; i += 256) {
        Wl[i] = W2l[i];
        Wr[i] = W2r[i];
    }
    __syncthreads();

    int wid  = threadIdx.x >> 6;
    int lane = threadIdx.x & 63;
    int g = lane >> 3;          // edge slot 0..7
    int l = lane & 7;           // feature block 0..7
    int n = blockIdx.x * 4 + wid;
    if (n >= N) return;
    int beg = row_ptr[n], end = row_ptr[n + 1];

    float a0[8] = {}, a1[8] = {};   // feats l*8+j and 64+l*8+j
    for (int eb = beg; eb < end; eb += 64) {
        int cnt = min(64, end - eb);
        int id = (eb + lane < end) ? csr_src[eb + lane] : 0;
        for (int t = 0; t < cnt; t += 8) {
            int src = __shfl(id, t + g);
            if (t + g < cnt) {
                const __bf16* row = pq + (size_t)src * 256;
                uint4 w0 = *(const uint4*)(row + l * 8);
                uint4 w1 = *(const uint4*)(row + 64 + l * 8);
                a0[0] += bf16_lo(w0.x); a0[1] += bf16_hi(w0.x);
                a0[2] += bf16_lo(w0.y); a0[3] += bf16_hi(w0.y);
                a0[4] += bf16_lo(w0.z); a0[5] += bf16_hi(w0.z);
                a0[6] += bf16_lo(w0.w); a0[7] += bf16_hi(w0.w);
                a1[0] += bf16_lo(w1.x); a1[1] += bf16_hi(w1.x);
                a1[2] += bf16_lo(w1.y); a1[3] += bf16_hi(w1.y);
                a1[4] += bf16_lo(w1.z); a1[5] += bf16_hi(w1.z);
                a1[6] += bf16_lo(w1.w); a1[7] += bf16_hi(w1.w);
            }
        }
    }
    #pragma unroll
    for (int c = 0; c < 8; ++c) {
        a0[c] += __shfl_xor(a0[c], 8);  a1[c] += __shfl_xor(a1[c], 8);
        a0[c] += __shfl_xor(a0[c], 16); a1[c] += __shfl_xor(a1[c], 16);
        a0[c] += __shfl_xor(a0[c], 32); a1[c] += __shfl_xor(a1[c], 32);
    }

    float inv = 1.0f / fmaxf((float)(end - beg), 1.0f);
    const __bf16* qrow = pq + (size_t)n * 256 + 128;
    uint4  qw0 = *(const uint4*)(qrow + l * 8);
    uint4  qw1 = *(const uint4*)(qrow + 64 + l * 8);
    float4 bv00 = *(const float4*)(b1 + l * 8);
    float4 bv01 = *(const float4*)(b1 + l * 8 + 4);
    float4 bv10 = *(const float4*)(b1 + 64 + l * 8);
    float4 bv11 = *(const float4*)(b1 + 64 + l * 8 + 4);
    float h0[8], h1[8];
    h0[0] = fmaxf(a0[0] * inv + bv00.x + bf16_lo(qw0.x), 0.f);
    h0[1] = fmaxf(a0[1] * inv + bv00.y + bf16_hi(qw0.x), 0.f);
    h0[2] = fmaxf(a0[2] * inv + bv00.z + bf16_lo(qw0.y), 0.f);
    h0[3] = fmaxf(a0[3] * inv + bv00.w + bf16_hi(qw0.y), 0.f);
    h0[4] = fmaxf(a0[4] * inv + bv01.x + bf16_lo(qw0.z), 0.f);
    h0[5] = fmaxf(a0[5] * inv + bv01.y + bf16_hi(qw0.z), 0.f);
    h0[6] = fmaxf(a0[6] * inv + bv01.z + bf16_lo(qw0.w), 0.f);
    h0[7] = fmaxf(a0[7] * inv + bv01.w + bf16_hi(qw0.w), 0.f);
    h1[0] = fmaxf(a1[0] * inv + bv10.x + bf16_lo(qw1.x), 0.f);
    h1[1] = fmaxf(a1[1] * inv + bv10.y + bf16_hi(qw1.x), 0.f);
    h1[2] = fmaxf(a1[2] * inv + bv10.z + bf16_lo(qw1.y), 0.f);
    h1[3] = fmaxf(a1[3] * inv + bv10.w + bf16_hi(qw1.y), 0.f);
    h1[4] = fmaxf(a1[4] * inv + bv11.x + bf16_lo(qw1.z), 0.f);
    h1[5] = fmaxf(a1[5] * inv + bv11.y + bf16_hi(qw1.z), 0.f);
    h1[6] = fmaxf(a1[6] * inv + bv11.z + bf16_lo(qw1.w), 0.f);
    h1[7] = fmaxf(a1[7] * inv + bv11.w + bf16_hi(qw1.w), 0.f);

    float part[8];
    #pragma unroll
    for (int c = 0; c < 4; ++c) {
        float pl = 0.f, pr = 0.f;
        #pragma unroll
        for (int j = 0; j < 8; ++j) {
            pl = fmaf(h0[j], Wl[c * 128 + l * 8 + j], pl);
            pl = fmaf(h1[j], Wl[c * 128 + 64 + l * 8 + j], pl);
            pr = fmaf(h0[j], Wr[c * 128 + l * 8 + j], pr);
            pr = fmaf(h1[j], Wr[c * 128 + 64 + l * 8 + j], pr);
        }
        part[c] = pl; part[4 + c] = pr;
    }
    #pragma unroll
    for (int off = 4; off; off >>= 1)
        #pragma unroll
        for (int c = 0; c < 8; ++c)
            part[c] += __shfl_xor(part[c], off);
    if (lane == 0) {
        *(float4*)(r + (size_t)n * 4) = make_float4(part[0], part[1], part[2], part[3]);
        *(float4*)(s + (size_t)n * 4) = make_float4(part[4], part[5], part[6], part[7]);
    }
}

// ---- layer 2: out[n] = mean_{src} r[src] + b2 + s[n]
__global__ __launch_bounds__(256)
void sage2_gather(const int* __restrict__ row_ptr, const int* __restrict__ csr_src,
                  const float* __restrict__ r, const float* __restrict__ s,
                  const float* __restrict__ b2, float* __restrict__ out, int N)
{
    int t = blockIdx.x * 256 + threadIdx.x;
    if (t >= N * 4) return;
    int n = t >> 2, c = t & 3;
    int beg = row_ptr[n], end = row_ptr[n + 1];
    float acc = 0.f;
    for (int e = beg; e < end; ++e)
        acc += r[(size_t)csr_src[e] * 4 + c];
    out[t] = acc / fmaxf((float)(end - beg), 1.0f) + b2[c] + s[t];
}

extern "C" void kernel_launch(void* const* d_in, const int* in_sizes, int n_in,
                              void* d_out, int out_size, void* d_ws, size_t ws_size,
                              hipStream_t stream)
{
    const float* x   = (const float*)d_in[0];
    const int*   ei  = (const int*)d_in[1];
    const float* W1l = (const float*)d_in[2];
    const float* b1l = (const float*)d_in[3];
    const float* W1r = (const float*)d_in[4];
    const float* W2l = (const float*)d_in[5];
    const float* b2l = (const float*)d_in[6];
    const float* W2r = (const float*)d_in[7];
    float* out = (float*)d_out;

    const int N = in_sizes[0] / 768;   // 50000
    const int E = in_sizes[1] / 2;     // 800000
    const int NB = (N + 1023) / 1024;  // 49 scan blocks
    const int gblocks = (N + 63) / 64;   // 782 gemm tiles (BN=256 full width)
    const int fblocks = (E + 511) / 512; // 1563 fill blocks, 1 edge/thread

    char* ws = (char*)d_ws;
    size_t off = 0;
    auto alloc = [&](size_t bytes) -> void* {
        void* pp = ws + off;
        off += (bytes + 255) & ~(size_t)255;
        return pp;
    };
    __bf16* pq      = (__bf16*)alloc((size_t)N * 256 * 2);
    float*  r       = (float*)alloc((size_t)N * 4 * 4);
    float*  s       = (float*)alloc((size_t)N * 4 * 4);
    __bf16* Bp      = (__bf16*)alloc((size_t)256 * 768 * 2);
    int*    deg     = (int*)alloc((size_t)N * 4);
    int*    row_ptr = (int*)alloc((size_t)(N + 1) * 4);
    int*    slot    = (int*)alloc((size_t)E * 4);
    int*    csr_src = (int*)alloc((size_t)E * 4);
    int*    partials= (int*)alloc((size_t)64 * 4);

    // ---- pack W fragment-major bf16 + zero deg
    prep<<<(256 * 768 + 255) / 256, 256, 0, stream>>>(W1l, W1r, Bp, deg, N);

    // ---- CSR: count (+slot) + scans (fill happens inside gemm_fill)
    csr_count<<<(E + 255) / 256, 256, 0, stream>>>(ei, deg, slot, E);
    scan1<<<NB, 1024, 0, stream>>>(deg, row_ptr, partials, N);
    scan23<<<NB, 1024, 0, stream>>>(row_ptr, partials, N, E, NB);

    // ---- fused csr_fill (first, retires fast) + layer-1 projection
    gemm_fill<<<fblocks + gblocks, 512, 0, stream>>>(x, Bp, pq, N, fblocks,
                                                     ei, row_ptr, slot,
                                                     csr_src, E);

    // ---- layer 1 aggregate + epilogue + layer-2 projection (fused)
    sage1_fused<<<(N + 3) / 4, 256, 0, stream>>>(row_ptr, csr_src, pq, b1l,
                                                 W2l, W2r, r, s, N);

    // ---- layer 2 aggregate + epilogue
    sage2_gather<<<(N * 4 + 255) / 256, 256, 0, stream>>>(row_ptr, csr_src, r, s, b2l, out, N);
}

// Round 22
// 185.737 us; speedup vs baseline: 1.9165x; 1.0027x over previous
//
#include <hip/hip_runtime.h>

// ---------------------------------------------------------------------------
// TextGraphSAGE: 2-layer SAGEConv (mean aggr), N=50000, D=768, H=128, C=4,
// E=800000.
//  - project BEFORE aggregating (mean commutes with linear map)
//  - CSR gather instead of scatter atomics (r1: 102M float atomics = 77%)
//  - r17 win: atomic-free slot-based fill; r18 win: r8 gemm engine
//  - r20/r21/r17 three-point experiment: fill-after = lonely tail (190),
//    fill-before = serial prologue (186), fill-interleaved = hidden (183).
//  - r22: block-granular interleave (every 3rd block = gemm tile, rest =
//    fill chunks) so fill hides under the whole gemm span; prefetch back
//    to 1-deep (r21's 2-deep cost occupancy, gained nothing).
// ---------------------------------------------------------------------------

typedef __bf16 bf16x8 __attribute__((ext_vector_type(8)));
typedef float  f32x4  __attribute__((ext_vector_type(4)));

__device__ __forceinline__ float bf16_lo(uint32_t w) {
    union { uint32_t u; float f; } c; c.u = w << 16; return c.f;
}
__device__ __forceinline__ float bf16_hi(uint32_t w) {
    union { uint32_t u; float f; } c; c.u = w & 0xffff0000u; return c.f;
}

// ---- prep: pack W into fragment-major bf16 Bp[kg][col][8] (kg=k/8, 96x256x8)
//      element (col,k) -> Bp[(k>>3)*2048 + col*8 + (k&7)]; also zero deg.
__global__ __launch_bounds__(256)
void prep(const float* __restrict__ W1l, const float* __restrict__ W1r,
          __bf16* __restrict__ Bp, int* __restrict__ deg, int N)
{
    int i = blockIdx.x * 256 + threadIdx.x;
    if (i < N) deg[i] = 0;
    if (i < 256 * 768) {
        int col = i / 768, k = i - col * 768;
        float v = (col < 128) ? W1l[col * 768 + k] : W1r[(col - 128) * 768 + k];
        Bp[((k >> 3) << 11) + (col << 3) + (k & 7)] = (__bf16)v;
    }
}

// ---- CSR build step 1: degree histogram + per-edge slot (atomic-free fill)
__global__ __launch_bounds__(256)
void csr_count(const int* __restrict__ ei, int* __restrict__ deg,
               int* __restrict__ slot, int E)
{
    int e = blockIdx.x * 256 + threadIdx.x;
    if (e >= E) return;
    slot[e] = atomicAdd(&deg[ei[E + e]], 1);
}

// ---- scan step 1: per-1024-block exclusive scan + block totals
__global__ __launch_bounds__(1024)
void scan1(const int* __restrict__ deg, int* __restrict__ row_ptr,
           int* __restrict__ partials, int N)
{
    __shared__ int buf[1024];
    int i = blockIdx.x * 1024 + threadIdx.x;
    int v = (i < N) ? deg[i] : 0;
    int val = v;
    buf[threadIdx.x] = val;
    __syncthreads();
    for (int off = 1; off < 1024; off <<= 1) {
        int t = (threadIdx.x >= (unsigned)off) ? buf[threadIdx.x - off] : 0;
        __syncthreads();
        val += t;
        buf[threadIdx.x] = val;
        __syncthreads();
    }
    if (i < N) row_ptr[i] = val - v;
    if (threadIdx.x == 1023) partials[blockIdx.x] = val;
}

// ---- scan steps 2+3 merged
__global__ __launch_bounds__(1024)
void scan23(int* __restrict__ row_ptr, const int* __restrict__ partials,
            int N, int E, int nb)
{
    __shared__ int soff;
    int b = blockIdx.x;
    if (threadIdx.x < 64) {
        int lane = threadIdx.x;
        int v = (lane < nb) ? partials[lane] : 0;
        int s = v;
        #pragma unroll
        for (int off = 1; off < 64; off <<= 1) {
            int t = __shfl_up(s, off);
            if (lane >= off) s += t;
        }
        if (lane == b) soff = s - v;
    }
    __syncthreads();
    int off = soff;
    int i = b * 1024 + threadIdx.x;
    if (i < N) row_ptr[i] += off;
    if (b == 0 && threadIdx.x == 0) row_ptr[N] = E;
}

// ---- fused, block-interleaved: blocks with b%3==0 are gemm tiles
// (bm = (b/3)*64); b%3 in {1,2} are csr_fill chunks (atomic-free).
// gemm: pq[M][256](bf16) = x[M][768](f32) @ W[256][768]^T.  r8 engine:
// 64x256 tile (A read ONCE), 512 threads (8 waves 2x4, wave-tile 32x64),
// BK=64, 1-deep A prefetch. B: per-lane fragment loads from L2-resident
// packed Bp. C: 4-pass LDS-staged coalesced stores reusing As (9.2KB LDS).
__global__ __launch_bounds__(512)
void gemm_fill(const float* __restrict__ A, const __bf16* __restrict__ Bp,
               __bf16* __restrict__ Cb, int M,
               const int* __restrict__ ei, const int* __restrict__ row_ptr,
               const int* __restrict__ slot, int* __restrict__ csr_src, int E)
{
    constexpr int LDK = 72;                  // +8 bf16 pad (144B row stride)
    __shared__ __bf16 As[64][LDK];           // 9.2 KB (staging + C-stage)
    const int tid = threadIdx.x;
    const int b  = blockIdx.x;
    const int g3 = b / 3, m3 = b - g3 * 3;

    if (m3 != 0) {
        // ------------- csr_fill: one edge per thread, NO atomics -------------
        int e = ((g3 << 1) + (m3 - 1)) * 512 + tid;
        if (e < E) {
            int src = ei[e];
            int dst = ei[E + e];
            csr_src[row_ptr[dst] + slot[e]] = src;
        }
        return;
    }

    // ---------------- gemm path (r8 engine, 1-deep prefetch) ----------------
    const int bm   = g3 * 64;
    const int lane = tid & 63;
    const int wave = tid >> 6;               // 0..7
    const int wr = wave >> 2, wc = wave & 3; // wave tile: 32 rows x 64 cols
    const int l15 = lane & 15;
    const int lk  = lane >> 4;               // 0..3

    f32x4 acc[2][4] = {};
    float4 apref[2];

    const int arow = tid >> 3;               // 0..63
    const int akc  = (tid & 7) << 3;         // 0..56
    const __bf16* bbase = Bp + ((size_t)(wc * 64 + l15) << 3) + ((size_t)lk << 11);

    auto load_A = [&](int k0) {
        if (bm + arow < M) {
            const float* src = A + (size_t)(bm + arow) * 768 + k0 + akc;
            apref[0] = *(const float4*)src;
            apref[1] = *(const float4*)(src + 4);
        } else {
            apref[0] = make_float4(0.f, 0.f, 0.f, 0.f);
            apref[1] = make_float4(0.f, 0.f, 0.f, 0.f);
        }
    };

    load_A(0);
    for (int kt = 0; kt < 12; ++kt) {
        if (kt) __syncthreads();             // MFMA of kt-1 done with LDS
        {
            float4 f0 = apref[0], f1 = apref[1];
            bf16x8 bb;
            bb[0] = (__bf16)f0.x; bb[1] = (__bf16)f0.y;
            bb[2] = (__bf16)f0.z; bb[3] = (__bf16)f0.w;
            bb[4] = (__bf16)f1.x; bb[5] = (__bf16)f1.y;
            bb[6] = (__bf16)f1.z; bb[7] = (__bf16)f1.w;
            *(bf16x8*)&As[arow][akc] = bb;
        }
        __syncthreads();
        if (kt < 11) load_A((kt + 1) * 64);  // A burst in flight across MFMA

        bf16x8 bcur[2][4];
        #pragma unroll
        for (int ks = 0; ks < 2; ++ks)
            #pragma unroll
            for (int j = 0; j < 4; ++j)
                bcur[ks][j] = *(const bf16x8*)(bbase +
                    (((size_t)(kt * 8 + ks * 4) << 11) + ((size_t)j << 7)));

        #pragma unroll
        for (int ks = 0; ks < 2; ++ks) {
            int koff = ks * 32 + lk * 8;
            bf16x8 af[2];
            #pragma unroll
            for (int i = 0; i < 2; ++i)
                af[i] = *(const bf16x8*)&As[wr * 32 + i * 16 + l15][koff];
            #pragma unroll
            for (int i = 0; i < 2; ++i)
                #pragma unroll
                for (int j = 0; j < 4; ++j)
                    acc[i][j] = __builtin_amdgcn_mfma_f32_16x16x32_bf16(
                        af[i], bcur[ks][j], acc[i][j], 0, 0, 0);
        }
    }

    // ---- coalesced C epilogue: 4 passes of 64 cols reusing As.
    // C/D layout: col = lane&15, row = (lane>>4)*4 + reg  [m89-verified]
    #pragma unroll
    for (int qtr = 0; qtr < 4; ++qtr) {
        __syncthreads();                     // prev pass stores / MFMA done
        if (wc == qtr) {
            #pragma unroll
            for (int i = 0; i < 2; ++i)
                #pragma unroll
                for (int j = 0; j < 4; ++j)
                    #pragma unroll
                    for (int v = 0; v < 4; ++v)
                        As[wr * 32 + i * 16 + lk * 4 + v][j * 16 + l15] =
                            (__bf16)acc[i][j][v];
        }
        __syncthreads();
        int row = tid >> 3, ch = tid & 7;
        if (bm + row < M)
            *(bf16x8*)(Cb + (size_t)(bm + row) * 256 + qtr * 64 + ch * 8) =
                *(const bf16x8*)&As[row][ch * 8];
    }
}

// ---- layer 1 + layer-2 projection, fused. One wave per node.
// 8 lanes per edge x 32B/lane (2 x uint4) -> 8 edges in flight / iteration.
__global__ __launch_bounds__(256)
void sage1_fused(const int* __restrict__ row_ptr, const int* __restrict__ csr_src,
                 const __bf16* __restrict__ pq, const float* __restrict__ b1,
                 const float* __restrict__ W2l, const float* __restrict__ W2r,
                 float* __restrict__ r, float* __restrict__ s, int N)
{
    __shared__ float Wl[512], Wr[512];
    for (int i = threadIdx.x; i < 512; i += 256) {
        Wl[i] = W2l[i];
        Wr[i] = W2r[i];
    }
    __syncthreads();

    int wid  = threadIdx.x >> 6;
    int lane = threadIdx.x & 63;
    int g = lane >> 3;          // edge slot 0..7
    int l = lane & 7;           // feature block 0..7
    int n = blockIdx.x * 4 + wid;
    if (n >= N) return;
    int beg = row_ptr[n], end = row_ptr[n + 1];

    float a0[8] = {}, a1[8] = {};   // feats l*8+j and 64+l*8+j
    for (int eb = beg; eb < end; eb += 64) {
        int cnt = min(64, end - eb);
        int id = (eb + lane < end) ? csr_src[eb + lane] : 0;
        for (int t = 0; t < cnt; t += 8) {
            int src = __shfl(id, t + g);
            if (t + g < cnt) {
                const __bf16* row = pq + (size_t)src * 256;
                uint4 w0 = *(const uint4*)(row + l * 8);
                uint4 w1 = *(const uint4*)(row + 64 + l * 8);
                a0[0] += bf16_lo(w0.x); a0[1] += bf16_hi(w0.x);
                a0[2] += bf16_lo(w0.y); a0[3] += bf16_hi(w0.y);
                a0[4] += bf16_lo(w0.z); a0[5] += bf16_hi(w0.z);
                a0[6] += bf16_lo(w0.w); a0[7] += bf16_hi(w0.w);
                a1[0] += bf16_lo(w1.x); a1[1] += bf16_hi(w1.x);
                a1[2] += bf16_lo(w1.y); a1[3] += bf16_hi(w1.y);
                a1[4] += bf16_lo(w1.z); a1[5] += bf16_hi(w1.z);
                a1[6] += bf16_lo(w1.w); a1[7] += bf16_hi(w1.w);
            }
        }
    }
    #pragma unroll
    for (int c = 0; c < 8; ++c) {
        a0[c] += __shfl_xor(a0[c], 8);  a1[c] += __shfl_xor(a1[c], 8);
        a0[c] += __shfl_xor(a0[c], 16); a1[c] += __shfl_xor(a1[c], 16);
        a0[c] += __shfl_xor(a0[c], 32); a1[c] += __shfl_xor(a1[c], 32);
    }

    float inv = 1.0f / fmaxf((float)(end - beg), 1.0f);
    const __bf16* qrow = pq + (size_t)n * 256 + 128;
    uint4  qw0 = *(const uint4*)(qrow + l * 8);
    uint4  qw1 = *(const uint4*)(qrow + 64 + l * 8);
    float4 bv00 = *(const float4*)(b1 + l * 8);
    float4 bv01 = *(const float4*)(b1 + l * 8 + 4);
    float4 bv10 = *(const float4*)(b1 + 64 + l * 8);
    float4 bv11 = *(const float4*)(b1 + 64 + l * 8 + 4);
    float h0[8], h1[8];
    h0[0] = fmaxf(a0[0] * inv + bv00.x + bf16_lo(qw0.x), 0.f);
    h0[1] = fmaxf(a0[1] * inv + bv00.y + bf16_hi(qw0.x), 0.f);
    h0[2] = fmaxf(a0[2] * inv + bv00.z + bf16_lo(qw0.y), 0.f);
    h0[3] = fmaxf(a0[3] * inv + bv00.w + bf16_hi(qw0.y), 0.f);
    h0[4] = fmaxf(a0[4] * inv + bv01.x + bf16_lo(qw0.z), 0.f);
    h0[5] = fmaxf(a0[5] * inv + bv01.y + bf16_hi(qw0.z), 0.f);
    h0[6] = fmaxf(a0[6] * inv + bv01.z + bf16_lo(qw0.w), 0.f);
    h0[7] = fmaxf(a0[7] * inv + bv01.w + bf16_hi(qw0.w), 0.f);
    h1[0] = fmaxf(a1[0] * inv + bv10.x + bf16_lo(qw1.x), 0.f);
    h1[1] = fmaxf(a1[1] * inv + bv10.y + bf16_hi(qw1.x), 0.f);
    h1[2] = fmaxf(a1[2] * inv + bv10.z + bf16_lo(qw1.y), 0.f);
    h1[3] = fmaxf(a1[3] * inv + bv10.w + bf16_hi(qw1.y), 0.f);
    h1[4] = fmaxf(a1[4] * inv + bv11.x + bf16_lo(qw1.z), 0.f);
    h1[5] = fmaxf(a1[5] * inv + bv11.y + bf16_hi(qw1.z), 0.f);
    h1[6] = fmaxf(a1[6] * inv + bv11.z + bf16_lo(qw1.w), 0.f);
    h1[7] = fmaxf(a1[7] * inv + bv11.w + bf16_hi(qw1.w), 0.f);

    float part[8];
    #pragma unroll
    for (int c = 0; c < 4; ++c) {
        float pl = 0.f, pr = 0.f;
        #pragma unroll
        for (int j = 0; j < 8; ++j) {
            pl = fmaf(h0[j], Wl[c * 128 + l * 8 + j], pl);
            pl = fmaf(h1[j], Wl[c * 128 + 64 + l * 8 + j], pl);
            pr = fmaf(h0[j], Wr[c * 128 + l * 8 + j], pr);
            pr = fmaf(h1[j], Wr[c * 128 + 64 + l * 8 + j], pr);
        }
        part[c] = pl; part[4 + c] = pr;
    }
    #pragma unroll
    for (int off = 4; off; off >>= 1)
        #pragma unroll
        for (int c = 0; c < 8; ++c)
            part[c] += __shfl_xor(part[c], off);
    if (lane == 0) {
        *(float4*)(r + (size_t)n * 4) = make_float4(part[0], part[1], part[2], part[3]);
        *(float4*)(s + (size_t)n * 4) = make_float4(part[4], part[5], part[6], part[7]);
    }
}

// ---- layer 2: out[n] = mean_{src} r[src] + b2 + s[n]
__global__ __launch_bounds__(256)
void sage2_gather(const int* __restrict__ row_ptr, const int* __restrict__ csr_src,
                  const float* __restrict__ r, const float* __restrict__ s,
                  const float* __restrict__ b2, float* __restrict__ out, int N)
{
    int t = blockIdx.x * 256 + threadIdx.x;
    if (t >= N * 4) return;
    int n = t >> 2, c = t & 3;
    int beg = row_ptr[n], end = row_ptr[n + 1];
    float acc = 0.f;
    for (int e = beg; e < end; ++e)
        acc += r[(size_t)csr_src[e] * 4 + c];
    out[t] = acc / fmaxf((float)(end - beg), 1.0f) + b2[c] + s[t];
}

extern "C" void kernel_launch(void* const* d_in, const int* in_sizes, int n_in,
                              void* d_out, int out_size, void* d_ws, size_t ws_size,
                              hipStream_t stream)
{
    const float* x   = (const float*)d_in[0];
    const int*   ei  = (const int*)d_in[1];
    const float* W1l = (const float*)d_in[2];
    const float* b1l = (const float*)d_in[3];
    const float* W1r = (const float*)d_in[4];
    const float* W2l = (const float*)d_in[5];
    const float* b2l = (const float*)d_in[6];
    const float* W2r = (const float*)d_in[7];
    float* out = (float*)d_out;

    const int N = in_sizes[0] / 768;   // 50000
    const int E = in_sizes[1] / 2;     // 800000
    const int NB = (N + 1023) / 1024;  // 49 scan blocks
    const int gblocks = (N + 63) / 64; // 782 gemm tiles (BN=256 full width)
    // interleaved grid: every 3rd block = gemm tile, others = fill chunks.
    // fill chunks needed: ceil(E/512) = 1563 <= gblocks*2 = 1564 (guarded).
    const int total = gblocks * 3;     // 2346 blocks

    char* ws = (char*)d_ws;
    size_t off = 0;
    auto alloc = [&](size_t bytes) -> void* {
        void* pp = ws + off;
        off += (bytes + 255) & ~(size_t)255;
        return pp;
    };
    __bf16* pq      = (__bf16*)alloc((size_t)N * 256 * 2);
    float*  r       = (float*)alloc((size_t)N * 4 * 4);
    float*  s       = (float*)alloc((size_t)N * 4 * 4);
    __bf16* Bp      = (__bf16*)alloc((size_t)256 * 768 * 2);
    int*    deg     = (int*)alloc((size_t)N * 4);
    int*    row_ptr = (int*)alloc((size_t)(N + 1) * 4);
    int*    slot    = (int*)alloc((size_t)E * 4);
    int*    csr_src = (int*)alloc((size_t)E * 4);
    int*    partials= (int*)alloc((size_t)64 * 4);

    // ---- pack W fragment-major bf16 + zero deg
    prep<<<(256 * 768 + 255) / 256, 256, 0, stream>>>(W1l, W1r, Bp, deg, N);

    // ---- CSR: count (+slot) + scans (fill happens inside gemm_fill)
    csr_count<<<(E + 255) / 256, 256, 0, stream>>>(ei, deg, slot, E);
    scan1<<<NB, 1024, 0, stream>>>(deg, row_ptr, partials, N);
    scan23<<<NB, 1024, 0, stream>>>(row_ptr, partials, N, E, NB);

    // ---- fused layer-1 projection + interleaved csr_fill
    gemm_fill<<<total, 512, 0, stream>>>(x, Bp, pq, N,
                                         ei, row_ptr, slot, csr_src, E);

    // ---- layer 1 aggregate + epilogue + layer-2 projection (fused)
    sage1_fused<<<(N + 3) / 4, 256, 0, stream>>>(row_ptr, csr_src, pq, b1l,
                                                 W2l, W2r, r, s, N);

    // ---- layer 2 aggregate + epilogue
    sage2_gather<<<(N * 4 + 255) / 256, 256, 0, stream>>>(row_ptr, csr_src, r, s, b2l, out, N);
}

// Round 23
// 183.533 us; speedup vs baseline: 1.9395x; 1.0120x over previous
//
#include <hip/hip_runtime.h>

// ---------------------------------------------------------------------------
// TextGraphSAGE: 2-layer SAGEConv (mean aggr), N=50000, D=768, H=128, C=4,
// E=800000.
//  - project BEFORE aggregating (mean commutes with linear map)
//  - CSR gather instead of scatter atomics (r1: 102M float atomics = 77%)
//  - r17: atomic-free slot fill; r18: r8 gemm engine; r22: block-granular
//    interleave hides fill under gemm (97->89us dispatch).
//  - r23: split the gemm in half -- dispatch A = tiles 0..390 + ALL count
//    chunks, scans, dispatch B = tiles 391..781 + ALL fill chunks. Both
//    CSR passes now hide under gemm halves; only the ~9us scans stay
//    serial. (Count was the last exposed ~15us.)
// ---------------------------------------------------------------------------

typedef __bf16 bf16x8 __attribute__((ext_vector_type(8)));
typedef float  f32x4  __attribute__((ext_vector_type(4)));

__device__ __forceinline__ float bf16_lo(uint32_t w) {
    union { uint32_t u; float f; } c; c.u = w << 16; return c.f;
}
__device__ __forceinline__ float bf16_hi(uint32_t w) {
    union { uint32_t u; float f; } c; c.u = w & 0xffff0000u; return c.f;
}

// ---- prep: pack W into fragment-major bf16 Bp[kg][col][8] (kg=k/8, 96x256x8)
//      element (col,k) -> Bp[(k>>3)*2048 + col*8 + (k&7)]; also zero deg.
__global__ __launch_bounds__(256)
void prep(const float* __restrict__ W1l, const float* __restrict__ W1r,
          __bf16* __restrict__ Bp, int* __restrict__ deg, int N)
{
    int i = blockIdx.x * 256 + threadIdx.x;
    if (i < N) deg[i] = 0;
    if (i < 256 * 768) {
        int col = i / 768, k = i - col * 768;
        float v = (col < 128) ? W1l[col * 768 + k] : W1r[(col - 128) * 768 + k];
        Bp[((k >> 3) << 11) + (col << 3) + (k & 7)] = (__bf16)v;
    }
}

// ---- scan step 1: per-1024-block exclusive scan + block totals
__global__ __launch_bounds__(1024)
void scan1(const int* __restrict__ deg, int* __restrict__ row_ptr,
           int* __restrict__ partials, int N)
{
    __shared__ int buf[1024];
    int i = blockIdx.x * 1024 + threadIdx.x;
    int v = (i < N) ? deg[i] : 0;
    int val = v;
    buf[threadIdx.x] = val;
    __syncthreads();
    for (int off = 1; off < 1024; off <<= 1) {
        int t = (threadIdx.x >= (unsigned)off) ? buf[threadIdx.x - off] : 0;
        __syncthreads();
        val += t;
        buf[threadIdx.x] = val;
        __syncthreads();
    }
    if (i < N) row_ptr[i] = val - v;
    if (threadIdx.x == 1023) partials[blockIdx.x] = val;
}

// ---- scan steps 2+3 merged
__global__ __launch_bounds__(1024)
void scan23(int* __restrict__ row_ptr, const int* __restrict__ partials,
            int N, int E, int nb)
{
    __shared__ int soff;
    int b = blockIdx.x;
    if (threadIdx.x < 64) {
        int lane = threadIdx.x;
        int v = (lane < nb) ? partials[lane] : 0;
        int s = v;
        #pragma unroll
        for (int off = 1; off < 64; off <<= 1) {
            int t = __shfl_up(s, off);
            if (lane >= off) s += t;
        }
        if (lane == b) soff = s - v;
    }
    __syncthreads();
    int off = soff;
    int i = b * 1024 + threadIdx.x;
    if (i < N) row_ptr[i] += off;
    if (b == 0 && threadIdx.x == 0) row_ptr[N] = E;
}

// ---- fused, block-interleaved: b%5==0 -> gemm tile (gstart + b/5);
// else -> edge chunk (count in MODE 0, fill in MODE 1), atomic-free fill.
// gemm: pq[M][256](bf16) = x[M][768](f32) @ W[256][768]^T.  r8 engine:
// 64x256 tile, 512 threads (8 waves 2x4, wave-tile 32x64), BK=64, 1-deep
// A prefetch. B: per-lane fragment loads from L2-resident packed Bp.
// C: 4-pass LDS-staged coalesced stores reusing As (9.2KB LDS).
template<int MODE>
__global__ __launch_bounds__(512)
void gemm_mixed(const float* __restrict__ A, const __bf16* __restrict__ Bp,
                __bf16* __restrict__ Cb, int M, int gstart,
                const int* __restrict__ ei, int* __restrict__ deg,
                const int* __restrict__ row_ptr, int* __restrict__ slot,
                int* __restrict__ csr_src, int E)
{
    constexpr int LDK = 72;                  // +8 bf16 pad (144B row stride)
    __shared__ __bf16 As[64][LDK];           // 9.2 KB (staging + C-stage)
    const int tid = threadIdx.x;
    const int b  = blockIdx.x;
    const int g5 = b / 5, m5 = b - g5 * 5;

    if (m5 != 0) {
        // --------- edge chunk: one edge per thread ---------
        int e = (g5 * 4 + (m5 - 1)) * 512 + tid;
        if (e < E) {
            if (MODE == 0) {                 // count + slot
                slot[e] = atomicAdd(&deg[ei[E + e]], 1);
            } else {                         // fill, atomic-free
                csr_src[row_ptr[ei[E + e]] + slot[e]] = ei[e];
            }
        }
        return;
    }

    // ---------------- gemm path (r8 engine, 1-deep prefetch) ----------------
    const int bm   = (gstart + g5) * 64;
    const int lane = tid & 63;
    const int wave = tid >> 6;               // 0..7
    const int wr = wave >> 2, wc = wave & 3; // wave tile: 32 rows x 64 cols
    const int l15 = lane & 15;
    const int lk  = lane >> 4;               // 0..3

    f32x4 acc[2][4] = {};
    float4 apref[2];

    const int arow = tid >> 3;               // 0..63
    const int akc  = (tid & 7) << 3;         // 0..56
    const __bf16* bbase = Bp + ((size_t)(wc * 64 + l15) << 3) + ((size_t)lk << 11);

    auto load_A = [&](int k0) {
        if (bm + arow < M) {
            const float* src = A + (size_t)(bm + arow) * 768 + k0 + akc;
            apref[0] = *(const float4*)src;
            apref[1] = *(const float4*)(src + 4);
        } else {
            apref[0] = make_float4(0.f, 0.f, 0.f, 0.f);
            apref[1] = make_float4(0.f, 0.f, 0.f, 0.f);
        }
    };

    load_A(0);
    for (int kt = 0; kt < 12; ++kt) {
        if (kt) __syncthreads();             // MFMA of kt-1 done with LDS
        {
            float4 f0 = apref[0], f1 = apref[1];
            bf16x8 bb;
            bb[0] = (__bf16)f0.x; bb[1] = (__bf16)f0.y;
            bb[2] = (__bf16)f0.z; bb[3] = (__bf16)f0.w;
            bb[4] = (__bf16)f1.x; bb[5] = (__bf16)f1.y;
            bb[6] = (__bf16)f1.z; bb[7] = (__bf16)f1.w;
            *(bf16x8*)&As[arow][akc] = bb;
        }
        __syncthreads();
        if (kt < 11) load_A((kt + 1) * 64);  // A burst in flight across MFMA

        bf16x8 bcur[2][4];
        #pragma unroll
        for (int ks = 0; ks < 2; ++ks)
            #pragma unroll
            for (int j = 0; j < 4; ++j)
                bcur[ks][j] = *(const bf16x8*)(bbase +
                    (((size_t)(kt * 8 + ks * 4) << 11) + ((size_t)j << 7)));

        #pragma unroll
        for (int ks = 0; ks < 2; ++ks) {
            int koff = ks * 32 + lk * 8;
            bf16x8 af[2];
            #pragma unroll
            for (int i = 0; i < 2; ++i)
                af[i] = *(const bf16x8*)&As[wr * 32 + i * 16 + l15][koff];
            #pragma unroll
            for (int i = 0; i < 2; ++i)
                #pragma unroll
                for (int j = 0; j < 4; ++j)
                    acc[i][j] = __builtin_amdgcn_mfma_f32_16x16x32_bf16(
                        af[i], bcur[ks][j], acc[i][j], 0, 0, 0);
        }
    }

    // ---- coalesced C epilogue: 4 passes of 64 cols reusing As.
    // C/D layout: col = lane&15, row = (lane>>4)*4 + reg  [m89-verified]
    #pragma unroll
    for (int qtr = 0; qtr < 4; ++qtr) {
        __syncthreads();                     // prev pass stores / MFMA done
        if (wc == qtr) {
            #pragma unroll
            for (int i = 0; i < 2; ++i)
                #pragma unroll
                for (int j = 0; j < 4; ++j)
                    #pragma unroll
                    for (int v = 0; v < 4; ++v)
                        As[wr * 32 + i * 16 + lk * 4 + v][j * 16 + l15] =
                            (__bf16)acc[i][j][v];
        }
        __syncthreads();
        int row = tid >> 3, ch = tid & 7;
        if (bm + row < M)
            *(bf16x8*)(Cb + (size_t)(bm + row) * 256 + qtr * 64 + ch * 8) =
                *(const bf16x8*)&As[row][ch * 8];
    }
}

// ---- layer 1 + layer-2 projection, fused. One wave per node.
// 8 lanes per edge x 32B/lane (2 x uint4) -> 8 edges in flight / iteration.
__global__ __launch_bounds__(256)
void sage1_fused(const int* __restrict__ row_ptr, const int* __restrict__ csr_src,
                 const __bf16* __restrict__ pq, const float* __restrict__ b1,
                 const float* __restrict__ W2l, const float* __restrict__ W2r,
                 float* __restrict__ r, float* __restrict__ s, int N)
{
    __shared__ float Wl[512], Wr[512];
    for (int i = threadIdx.x; i < 512; i += 256) {
        Wl[i] = W2l[i];
        Wr[i] = W2r[i];
    }
    __syncthreads();

    int wid  = threadIdx.x >> 6;
    int lane = threadIdx.x & 63;
    int g = lane >> 3;          // edge slot 0..7
    int l = lane & 7;           // feature block 0..7
    int n = blockIdx.x * 4 + wid;
    if (n >= N) return;
    int beg = row_ptr[n], end = row_ptr[n + 1];

    float a0[8] = {}, a1[8] = {};   // feats l*8+j and 64+l*8+j
    for (int eb = beg; eb < end; eb += 64) {
        int cnt = min(64, end - eb);
        int id = (eb + lane < end) ? csr_src[eb + lane] : 0;
        for (int t = 0; t < cnt; t += 8) {
            int src = __shfl(id, t + g);
            if (t + g < cnt) {
                const __bf16* row = pq + (size_t)src * 256;
                uint4 w0 = *(const uint4*)(row + l * 8);
                uint4 w1 = *(const uint4*)(row + 64 + l * 8);
                a0[0] += bf16_lo(w0.x); a0[1] += bf16_hi(w0.x);
                a0[2] += bf16_lo(w0.y); a0[3] += bf16_hi(w0.y);
                a0[4] += bf16_lo(w0.z); a0[5] += bf16_hi(w0.z);
                a0[6] += bf16_lo(w0.w); a0[7] += bf16_hi(w0.w);
                a1[0] += bf16_lo(w1.x); a1[1] += bf16_hi(w1.x);
                a1[2] += bf16_lo(w1.y); a1[3] += bf16_hi(w1.y);
                a1[4] += bf16_lo(w1.z); a1[5] += bf16_hi(w1.z);
                a1[6] += bf16_lo(w1.w); a1[7] += bf16_hi(w1.w);
            }
        }
    }
    #pragma unroll
    for (int c = 0; c < 8; ++c) {
        a0[c] += __shfl_xor(a0[c], 8);  a1[c] += __shfl_xor(a1[c], 8);
        a0[c] += __shfl_xor(a0[c], 16); a1[c] += __shfl_xor(a1[c], 16);
        a0[c] += __shfl_xor(a0[c], 32); a1[c] += __shfl_xor(a1[c], 32);
    }

    float inv = 1.0f / fmaxf((float)(end - beg), 1.0f);
    const __bf16* qrow = pq + (size_t)n * 256 + 128;
    uint4  qw0 = *(const uint4*)(qrow + l * 8);
    uint4  qw1 = *(const uint4*)(qrow + 64 + l * 8);
    float4 bv00 = *(const float4*)(b1 + l * 8);
    float4 bv01 = *(const float4*)(b1 + l * 8 + 4);
    float4 bv10 = *(const float4*)(b1 + 64 + l * 8);
    float4 bv11 = *(const float4*)(b1 + 64 + l * 8 + 4);
    float h0[8], h1[8];
    h0[0] = fmaxf(a0[0] * inv + bv00.x + bf16_lo(qw0.x), 0.f);
    h0[1] = fmaxf(a0[1] * inv + bv00.y + bf16_hi(qw0.x), 0.f);
    h0[2] = fmaxf(a0[2] * inv + bv00.z + bf16_lo(qw0.y), 0.f);
    h0[3] = fmaxf(a0[3] * inv + bv00.w + bf16_hi(qw0.y), 0.f);
    h0[4] = fmaxf(a0[4] * inv + bv01.x + bf16_lo(qw0.z), 0.f);
    h0[5] = fmaxf(a0[5] * inv + bv01.y + bf16_hi(qw0.z), 0.f);
    h0[6] = fmaxf(a0[6] * inv + bv01.z + bf16_lo(qw0.w), 0.f);
    h0[7] = fmaxf(a0[7] * inv + bv01.w + bf16_hi(qw0.w), 0.f);
    h1[0] = fmaxf(a1[0] * inv + bv10.x + bf16_lo(qw1.x), 0.f);
    h1[1] = fmaxf(a1[1] * inv + bv10.y + bf16_hi(qw1.x), 0.f);
    h1[2] = fmaxf(a1[2] * inv + bv10.z + bf16_lo(qw1.y), 0.f);
    h1[3] = fmaxf(a1[3] * inv + bv10.w + bf16_hi(qw1.y), 0.f);
    h1[4] = fmaxf(a1[4] * inv + bv11.x + bf16_lo(qw1.z), 0.f);
    h1[5] = fmaxf(a1[5] * inv + bv11.y + bf16_hi(qw1.z), 0.f);
    h1[6] = fmaxf(a1[6] * inv + bv11.z + bf16_lo(qw1.w), 0.f);
    h1[7] = fmaxf(a1[7] * inv + bv11.w + bf16_hi(qw1.w), 0.f);

    float part[8];
    #pragma unroll
    for (int c = 0; c < 4; ++c) {
        float pl = 0.f, pr = 0.f;
        #pragma unroll
        for (int j = 0; j < 8; ++j) {
            pl = fmaf(h0[j], Wl[c * 128 + l * 8 + j], pl);
            pl = fmaf(h1[j], Wl[c * 128 + 64 + l * 8 + j], pl);
            pr = fmaf(h0[j], Wr[c * 128 + l * 8 + j], pr);
            pr = fmaf(h1[j], Wr[c * 128 + 64 + l * 8 + j], pr);
        }
        part[c] = pl; part[4 + c] = pr;
    }
    #pragma unroll
    for (int off = 4; off; off >>= 1)
        #pragma unroll
        for (int c = 0; c < 8; ++c)
            part[c] += __shfl_xor(part[c], off);
    if (lane == 0) {
        *(float4*)(r + (size_t)n * 4) = make_float4(part[0], part[1], part[2], part[3]);
        *(float4*)(s + (size_t)n * 4) = make_float4(part[4], part[5], part[6], part[7]);
    }
}

// ---- layer 2: out[n] = mean_{src} r[src] + b2 + s[n]
__global__ __launch_bounds__(256)
void sage2_gather(const int* __restrict__ row_ptr, const int* __restrict__ csr_src,
                  const float* __restrict__ r, const float* __restrict__ s,
                  const float* __restrict__ b2, float* __restrict__ out, int N)
{
    int t = blockIdx.x * 256 + threadIdx.x;
    if (t >= N * 4) return;
    int n = t >> 2, c = t & 3;
    int beg = row_ptr[n], end = row_ptr[n + 1];
    float acc = 0.f;
    for (int e = beg; e < end; ++e)
        acc += r[(size_t)csr_src[e] * 4 + c];
    out[t] = acc / fmaxf((float)(end - beg), 1.0f) + b2[c] + s[t];
}

extern "C" void kernel_launch(void* const* d_in, const int* in_sizes, int n_in,
                              void* d_out, int out_size, void* d_ws, size_t ws_size,
                              hipStream_t stream)
{
    const float* x   = (const float*)d_in[0];
    const int*   ei  = (const int*)d_in[1];
    const float* W1l = (const float*)d_in[2];
    const float* b1l = (const float*)d_in[3];
    const float* W1r = (const float*)d_in[4];
    const float* W2l = (const float*)d_in[5];
    const float* b2l = (const float*)d_in[6];
    const float* W2r = (const float*)d_in[7];
    float* out = (float*)d_out;

    const int N = in_sizes[0] / 768;   // 50000
    const int E = in_sizes[1] / 2;     // 800000
    const int NB = (N + 1023) / 1024;  // 49 scan blocks
    const int gblocks = (N + 63) / 64; // 782 gemm tiles (BN=256 full width)
    const int ghalf1  = gblocks / 2;   // 391 tiles in dispatch A
    const int ghalf2  = gblocks - ghalf1; // 391 tiles in dispatch B
    // each dispatch: per gemm tile 4 edge chunks of 512 -> 4*391=1564 >= 1563
    // chunks needed (ceil(E/512)); guarded by e<E.

    char* ws = (char*)d_ws;
    size_t off = 0;
    auto alloc = [&](size_t bytes) -> void* {
        void* pp = ws + off;
        off += (bytes + 255) & ~(size_t)255;
        return pp;
    };
    __bf16* pq      = (__bf16*)alloc((size_t)N * 256 * 2);
    float*  r       = (float*)alloc((size_t)N * 4 * 4);
    float*  s       = (float*)alloc((size_t)N * 4 * 4);
    __bf16* Bp      = (__bf16*)alloc((size_t)256 * 768 * 2);
    int*    deg     = (int*)alloc((size_t)N * 4);
    int*    row_ptr = (int*)alloc((size_t)(N + 1) * 4);
    int*    slot    = (int*)alloc((size_t)E * 4);
    int*    csr_src = (int*)alloc((size_t)E * 4);
    int*    partials= (int*)alloc((size_t)64 * 4);

    // ---- pack W fragment-major bf16 + zero deg
    prep<<<(256 * 768 + 255) / 256, 256, 0, stream>>>(W1l, W1r, Bp, deg, N);

    // ---- dispatch A: gemm tiles 0..ghalf1-1 + ALL csr_count chunks
    gemm_mixed<0><<<ghalf1 * 5, 512, 0, stream>>>(x, Bp, pq, N, 0,
                                                  ei, deg, row_ptr, slot,
                                                  csr_src, E);

    // ---- scans (only serial CSR cost left)
    scan1<<<NB, 1024, 0, stream>>>(deg, row_ptr, partials, N);
    scan23<<<NB, 1024, 0, stream>>>(row_ptr, partials, N, E, NB);

    // ---- dispatch B: gemm tiles ghalf1..gblocks-1 + ALL csr_fill chunks
    gemm_mixed<1><<<ghalf2 * 5, 512, 0, stream>>>(x, Bp, pq, N, ghalf1,
                                                  ei, deg, row_ptr, slot,
                                                  csr_src, E);

    // ---- layer 1 aggregate + epilogue + layer-2 projection (fused)
    sage1_fused<<<(N + 3) / 4, 256, 0, stream>>>(row_ptr, csr_src, pq, b1l,
                                                 W2l, W2r, r, s, N);

    // ---- layer 2 aggregate + epilogue
    sage2_gather<<<(N * 4 + 255) / 256, 256, 0, stream>>>(row_ptr, csr_src, r, s, b2l, out, N);
}

// Round 24
// 180.876 us; speedup vs baseline: 1.9680x; 1.0147x over previous
//
#include <hip/hip_runtime.h>

// ---------------------------------------------------------------------------
// TextGraphSAGE: 2-layer SAGEConv (mean aggr), N=50000, D=768, H=128, C=4,
// E=800000.
//  - project BEFORE aggregating (mean commutes with linear map)
//  - CSR gather instead of scatter atomics (r1: 102M float atomics = 77%)
//  - r17: atomic-free slot fill; r18: r8 gemm engine; r22/r23: count+fill
//    hidden under gemm halves via block-granular interleave.
//  - r24: sage1 inner loop software-pipelined x2 (two 8-edge groups per
//    iteration -> 4 uint4 in flight/lane, fold width UNCHANGED -- r19
//    lesson). Per-lane accumulation order preserved (bit-identical).
// ---------------------------------------------------------------------------

typedef __bf16 bf16x8 __attribute__((ext_vector_type(8)));
typedef float  f32x4  __attribute__((ext_vector_type(4)));

__device__ __forceinline__ float bf16_lo(uint32_t w) {
    union { uint32_t u; float f; } c; c.u = w << 16; return c.f;
}
__device__ __forceinline__ float bf16_hi(uint32_t w) {
    union { uint32_t u; float f; } c; c.u = w & 0xffff0000u; return c.f;
}

// ---- prep: pack W into fragment-major bf16 Bp[kg][col][8] (kg=k/8, 96x256x8)
//      element (col,k) -> Bp[(k>>3)*2048 + col*8 + (k&7)]; also zero deg.
__global__ __launch_bounds__(256)
void prep(const float* __restrict__ W1l, const float* __restrict__ W1r,
          __bf16* __restrict__ Bp, int* __restrict__ deg, int N)
{
    int i = blockIdx.x * 256 + threadIdx.x;
    if (i < N) deg[i] = 0;
    if (i < 256 * 768) {
        int col = i / 768, k = i - col * 768;
        float v = (col < 128) ? W1l[col * 768 + k] : W1r[(col - 128) * 768 + k];
        Bp[((k >> 3) << 11) + (col << 3) + (k & 7)] = (__bf16)v;
    }
}

// ---- scan step 1: per-1024-block exclusive scan + block totals
__global__ __launch_bounds__(1024)
void scan1(const int* __restrict__ deg, int* __restrict__ row_ptr,
           int* __restrict__ partials, int N)
{
    __shared__ int buf[1024];
    int i = blockIdx.x * 1024 + threadIdx.x;
    int v = (i < N) ? deg[i] : 0;
    int val = v;
    buf[threadIdx.x] = val;
    __syncthreads();
    for (int off = 1; off < 1024; off <<= 1) {
        int t = (threadIdx.x >= (unsigned)off) ? buf[threadIdx.x - off] : 0;
        __syncthreads();
        val += t;
        buf[threadIdx.x] = val;
        __syncthreads();
    }
    if (i < N) row_ptr[i] = val - v;
    if (threadIdx.x == 1023) partials[blockIdx.x] = val;
}

// ---- scan steps 2+3 merged
__global__ __launch_bounds__(1024)
void scan23(int* __restrict__ row_ptr, const int* __restrict__ partials,
            int N, int E, int nb)
{
    __shared__ int soff;
    int b = blockIdx.x;
    if (threadIdx.x < 64) {
        int lane = threadIdx.x;
        int v = (lane < nb) ? partials[lane] : 0;
        int s = v;
        #pragma unroll
        for (int off = 1; off < 64; off <<= 1) {
            int t = __shfl_up(s, off);
            if (lane >= off) s += t;
        }
        if (lane == b) soff = s - v;
    }
    __syncthreads();
    int off = soff;
    int i = b * 1024 + threadIdx.x;
    if (i < N) row_ptr[i] += off;
    if (b == 0 && threadIdx.x == 0) row_ptr[N] = E;
}

// ---- fused, block-interleaved: b%5==0 -> gemm tile (gstart + b/5);
// else -> edge chunk (count in MODE 0, fill in MODE 1), atomic-free fill.
template<int MODE>
__global__ __launch_bounds__(512)
void gemm_mixed(const float* __restrict__ A, const __bf16* __restrict__ Bp,
                __bf16* __restrict__ Cb, int M, int gstart,
                const int* __restrict__ ei, int* __restrict__ deg,
                const int* __restrict__ row_ptr, int* __restrict__ slot,
                int* __restrict__ csr_src, int E)
{
    constexpr int LDK = 72;                  // +8 bf16 pad (144B row stride)
    __shared__ __bf16 As[64][LDK];           // 9.2 KB (staging + C-stage)
    const int tid = threadIdx.x;
    const int b  = blockIdx.x;
    const int g5 = b / 5, m5 = b - g5 * 5;

    if (m5 != 0) {
        // --------- edge chunk: one edge per thread ---------
        int e = (g5 * 4 + (m5 - 1)) * 512 + tid;
        if (e < E) {
            if (MODE == 0) {                 // count + slot
                slot[e] = atomicAdd(&deg[ei[E + e]], 1);
            } else {                         // fill, atomic-free
                csr_src[row_ptr[ei[E + e]] + slot[e]] = ei[e];
            }
        }
        return;
    }

    // ---------------- gemm path (r8 engine, 1-deep prefetch) ----------------
    const int bm   = (gstart + g5) * 64;
    const int lane = tid & 63;
    const int wave = tid >> 6;               // 0..7
    const int wr = wave >> 2, wc = wave & 3; // wave tile: 32 rows x 64 cols
    const int l15 = lane & 15;
    const int lk  = lane >> 4;               // 0..3

    f32x4 acc[2][4] = {};
    float4 apref[2];

    const int arow = tid >> 3;               // 0..63
    const int akc  = (tid & 7) << 3;         // 0..56
    const __bf16* bbase = Bp + ((size_t)(wc * 64 + l15) << 3) + ((size_t)lk << 11);

    auto load_A = [&](int k0) {
        if (bm + arow < M) {
            const float* src = A + (size_t)(bm + arow) * 768 + k0 + akc;
            apref[0] = *(const float4*)src;
            apref[1] = *(const float4*)(src + 4);
        } else {
            apref[0] = make_float4(0.f, 0.f, 0.f, 0.f);
            apref[1] = make_float4(0.f, 0.f, 0.f, 0.f);
        }
    };

    load_A(0);
    for (int kt = 0; kt < 12; ++kt) {
        if (kt) __syncthreads();             // MFMA of kt-1 done with LDS
        {
            float4 f0 = apref[0], f1 = apref[1];
            bf16x8 bb;
            bb[0] = (__bf16)f0.x; bb[1] = (__bf16)f0.y;
            bb[2] = (__bf16)f0.z; bb[3] = (__bf16)f0.w;
            bb[4] = (__bf16)f1.x; bb[5] = (__bf16)f1.y;
            bb[6] = (__bf16)f1.z; bb[7] = (__bf16)f1.w;
            *(bf16x8*)&As[arow][akc] = bb;
        }
        __syncthreads();
        if (kt < 11) load_A((kt + 1) * 64);  // A burst in flight across MFMA

        bf16x8 bcur[2][4];
        #pragma unroll
        for (int ks = 0; ks < 2; ++ks)
            #pragma unroll
            for (int j = 0; j < 4; ++j)
                bcur[ks][j] = *(const bf16x8*)(bbase +
                    (((size_t)(kt * 8 + ks * 4) << 11) + ((size_t)j << 7)));

        #pragma unroll
        for (int ks = 0; ks < 2; ++ks) {
            int koff = ks * 32 + lk * 8;
            bf16x8 af[2];
            #pragma unroll
            for (int i = 0; i < 2; ++i)
                af[i] = *(const bf16x8*)&As[wr * 32 + i * 16 + l15][koff];
            #pragma unroll
            for (int i = 0; i < 2; ++i)
                #pragma unroll
                for (int j = 0; j < 4; ++j)
                    acc[i][j] = __builtin_amdgcn_mfma_f32_16x16x32_bf16(
                        af[i], bcur[ks][j], acc[i][j], 0, 0, 0);
        }
    }

    // ---- coalesced C epilogue: 4 passes of 64 cols reusing As.
    // C/D layout: col = lane&15, row = (lane>>4)*4 + reg  [m89-verified]
    #pragma unroll
    for (int qtr = 0; qtr < 4; ++qtr) {
        __syncthreads();                     // prev pass stores / MFMA done
        if (wc == qtr) {
            #pragma unroll
            for (int i = 0; i < 2; ++i)
                #pragma unroll
                for (int j = 0; j < 4; ++j)
                    #pragma unroll
                    for (int v = 0; v < 4; ++v)
                        As[wr * 32 + i * 16 + lk * 4 + v][j * 16 + l15] =
                            (__bf16)acc[i][j][v];
        }
        __syncthreads();
        int row = tid >> 3, ch = tid & 7;
        if (bm + row < M)
            *(bf16x8*)(Cb + (size_t)(bm + row) * 256 + qtr * 64 + ch * 8) =
                *(const bf16x8*)&As[row][ch * 8];
    }
}

// ---- layer 1 + layer-2 projection, fused. One wave per node.
// 8 lanes per edge x 32B/lane; inner loop pipelined x2 (two 8-edge groups
// per iteration -> 4 uint4 in flight/lane). Fold width unchanged (r19).
__global__ __launch_bounds__(256)
void sage1_fused(const int* __restrict__ row_ptr, const int* __restrict__ csr_src,
                 const __bf16* __restrict__ pq, const float* __restrict__ b1,
                 const float* __restrict__ W2l, const float* __restrict__ W2r,
                 float* __restrict__ r, float* __restrict__ s, int N)
{
    __shared__ float Wl[512], Wr[512];
    for (int i = threadIdx.x; i < 512; i += 256) {
        Wl[i] = W2l[i];
        Wr[i] = W2r[i];
    }
    __syncthreads();

    int wid  = threadIdx.x >> 6;
    int lane = threadIdx.x & 63;
    int g = lane >> 3;          // edge slot 0..7
    int l = lane & 7;           // feature block 0..7
    int n = blockIdx.x * 4 + wid;
    if (n >= N) return;
    int beg = row_ptr[n], end = row_ptr[n + 1];

    float a0[8] = {}, a1[8] = {};   // feats l*8+j and 64+l*8+j
    for (int eb = beg; eb < end; eb += 64) {
        int cnt = min(64, end - eb);
        int id = (eb + lane < end) ? csr_src[eb + lane] : 0;
        for (int t = 0; t < cnt; t += 16) {
            // two 8-edge groups pipelined: issue all 4 row-loads, then acc
            int src0 = __shfl(id, t + g);
            int src1 = __shfl(id, t + 8 + g);
            bool ok0 = (t + g < cnt);
            bool ok1 = (t + 8 + g < cnt);
            const __bf16* row0 = pq + (size_t)src0 * 256;
            const __bf16* row1 = pq + (size_t)src1 * 256;
            uint4 w0a, w1a, w0b, w1b;
            if (ok0) {
                w0a = *(const uint4*)(row0 + l * 8);
                w1a = *(const uint4*)(row0 + 64 + l * 8);
            }
            if (ok1) {
                w0b = *(const uint4*)(row1 + l * 8);
                w1b = *(const uint4*)(row1 + 64 + l * 8);
            }
            if (ok0) {
                a0[0] += bf16_lo(w0a.x); a0[1] += bf16_hi(w0a.x);
                a0[2] += bf16_lo(w0a.y); a0[3] += bf16_hi(w0a.y);
                a0[4] += bf16_lo(w0a.z); a0[5] += bf16_hi(w0a.z);
                a0[6] += bf16_lo(w0a.w); a0[7] += bf16_hi(w0a.w);
                a1[0] += bf16_lo(w1a.x); a1[1] += bf16_hi(w1a.x);
                a1[2] += bf16_lo(w1a.y); a1[3] += bf16_hi(w1a.y);
                a1[4] += bf16_lo(w1a.z); a1[5] += bf16_hi(w1a.z);
                a1[6] += bf16_lo(w1a.w); a1[7] += bf16_hi(w1a.w);
            }
            if (ok1) {
                a0[0] += bf16_lo(w0b.x); a0[1] += bf16_hi(w0b.x);
                a0[2] += bf16_lo(w0b.y); a0[3] += bf16_hi(w0b.y);
                a0[4] += bf16_lo(w0b.z); a0[5] += bf16_hi(w0b.z);
                a0[6] += bf16_lo(w0b.w); a0[7] += bf16_hi(w0b.w);
                a1[0] += bf16_lo(w1b.x); a1[1] += bf16_hi(w1b.x);
                a1[2] += bf16_lo(w1b.y); a1[3] += bf16_hi(w1b.y);
                a1[4] += bf16_lo(w1b.z); a1[5] += bf16_hi(w1b.z);
                a1[6] += bf16_lo(w1b.w); a1[7] += bf16_hi(w1b.w);
            }
        }
    }
    #pragma unroll
    for (int c = 0; c < 8; ++c) {
        a0[c] += __shfl_xor(a0[c], 8);  a1[c] += __shfl_xor(a1[c], 8);
        a0[c] += __shfl_xor(a0[c], 16); a1[c] += __shfl_xor(a1[c], 16);
        a0[c] += __shfl_xor(a0[c], 32); a1[c] += __shfl_xor(a1[c], 32);
    }

    float inv = 1.0f / fmaxf((float)(end - beg), 1.0f);
    const __bf16* qrow = pq + (size_t)n * 256 + 128;
    uint4  qw0 = *(const uint4*)(qrow + l * 8);
    uint4  qw1 = *(const uint4*)(qrow + 64 + l * 8);
    float4 bv00 = *(const float4*)(b1 + l * 8);
    float4 bv01 = *(const float4*)(b1 + l * 8 + 4);
    float4 bv10 = *(const float4*)(b1 + 64 + l * 8);
    float4 bv11 = *(const float4*)(b1 + 64 + l * 8 + 4);
    float h0[8], h1[8];
    h0[0] = fmaxf(a0[0] * inv + bv00.x + bf16_lo(qw0.x), 0.f);
    h0[1] = fmaxf(a0[1] * inv + bv00.y + bf16_hi(qw0.x), 0.f);
    h0[2] = fmaxf(a0[2] * inv + bv00.z + bf16_lo(qw0.y), 0.f);
    h0[3] = fmaxf(a0[3] * inv + bv00.w + bf16_hi(qw0.y), 0.f);
    h0[4] = fmaxf(a0[4] * inv + bv01.x + bf16_lo(qw0.z), 0.f);
    h0[5] = fmaxf(a0[5] * inv + bv01.y + bf16_hi(qw0.z), 0.f);
    h0[6] = fmaxf(a0[6] * inv + bv01.z + bf16_lo(qw0.w), 0.f);
    h0[7] = fmaxf(a0[7] * inv + bv01.w + bf16_hi(qw0.w), 0.f);
    h1[0] = fmaxf(a1[0] * inv + bv10.x + bf16_lo(qw1.x), 0.f);
    h1[1] = fmaxf(a1[1] * inv + bv10.y + bf16_hi(qw1.x), 0.f);
    h1[2] = fmaxf(a1[2] * inv + bv10.z + bf16_lo(qw1.y), 0.f);
    h1[3] = fmaxf(a1[3] * inv + bv10.w + bf16_hi(qw1.y), 0.f);
    h1[4] = fmaxf(a1[4] * inv + bv11.x + bf16_lo(qw1.z), 0.f);
    h1[5] = fmaxf(a1[5] * inv + bv11.y + bf16_hi(qw1.z), 0.f);
    h1[6] = fmaxf(a1[6] * inv + bv11.z + bf16_lo(qw1.w), 0.f);
    h1[7] = fmaxf(a1[7] * inv + bv11.w + bf16_hi(qw1.w), 0.f);

    float part[8];
    #pragma unroll
    for (int c = 0; c < 4; ++c) {
        float pl = 0.f, pr = 0.f;
        #pragma unroll
        for (int j = 0; j < 8; ++j) {
            pl = fmaf(h0[j], Wl[c * 128 + l * 8 + j], pl);
            pl = fmaf(h1[j], Wl[c * 128 + 64 + l * 8 + j], pl);
            pr = fmaf(h0[j], Wr[c * 128 + l * 8 + j], pr);
            pr = fmaf(h1[j], Wr[c * 128 + 64 + l * 8 + j], pr);
        }
        part[c] = pl; part[4 + c] = pr;
    }
    #pragma unroll
    for (int off = 4; off; off >>= 1)
        #pragma unroll
        for (int c = 0; c < 8; ++c)
            part[c] += __shfl_xor(part[c], off);
    if (lane == 0) {
        *(float4*)(r + (size_t)n * 4) = make_float4(part[0], part[1], part[2], part[3]);
        *(float4*)(s + (size_t)n * 4) = make_float4(part[4], part[5], part[6], part[7]);
    }
}

// ---- layer 2: out[n] = mean_{src} r[src] + b2 + s[n]
__global__ __launch_bounds__(256)
void sage2_gather(const int* __restrict__ row_ptr, const int* __restrict__ csr_src,
                  const float* __restrict__ r, const float* __restrict__ s,
                  const float* __restrict__ b2, float* __restrict__ out, int N)
{
    int t = blockIdx.x * 256 + threadIdx.x;
    if (t >= N * 4) return;
    int n = t >> 2, c = t & 3;
    int beg = row_ptr[n], end = row_ptr[n + 1];
    float acc = 0.f;
    for (int e = beg; e < end; ++e)
        acc += r[(size_t)csr_src[e] * 4 + c];
    out[t] = acc / fmaxf((float)(end - beg), 1.0f) + b2[c] + s[t];
}

extern "C" void kernel_launch(void* const* d_in, const int* in_sizes, int n_in,
                              void* d_out, int out_size, void* d_ws, size_t ws_size,
                              hipStream_t stream)
{
    const float* x   = (const float*)d_in[0];
    const int*   ei  = (const int*)d_in[1];
    const float* W1l = (const float*)d_in[2];
    const float* b1l = (const float*)d_in[3];
    const float* W1r = (const float*)d_in[4];
    const float* W2l = (const float*)d_in[5];
    const float* b2l = (const float*)d_in[6];
    const float* W2r = (const float*)d_in[7];
    float* out = (float*)d_out;

    const int N = in_sizes[0] / 768;   // 50000
    const int E = in_sizes[1] / 2;     // 800000
    const int NB = (N + 1023) / 1024;  // 49 scan blocks
    const int gblocks = (N + 63) / 64; // 782 gemm tiles (BN=256 full width)
    const int ghalf1  = gblocks / 2;   // 391 tiles in dispatch A
    const int ghalf2  = gblocks - ghalf1; // 391 tiles in dispatch B

    char* ws = (char*)d_ws;
    size_t off = 0;
    auto alloc = [&](size_t bytes) -> void* {
        void* pp = ws + off;
        off += (bytes + 255) & ~(size_t)255;
        return pp;
    };
    __bf16* pq      = (__bf16*)alloc((size_t)N * 256 * 2);
    float*  r       = (float*)alloc((size_t)N * 4 * 4);
    float*  s       = (float*)alloc((size_t)N * 4 * 4);
    __bf16* Bp      = (__bf16*)alloc((size_t)256 * 768 * 2);
    int*    deg     = (int*)alloc((size_t)N * 4);
    int*    row_ptr = (int*)alloc((size_t)(N + 1) * 4);
    int*    slot    = (int*)alloc((size_t)E * 4);
    int*    csr_src = (int*)alloc((size_t)E * 4);
    int*    partials= (int*)alloc((size_t)64 * 4);

    // ---- pack W fragment-major bf16 + zero deg
    prep<<<(256 * 768 + 255) / 256, 256, 0, stream>>>(W1l, W1r, Bp, deg, N);

    // ---- dispatch A: gemm tiles 0..ghalf1-1 + ALL csr_count chunks
    gemm_mixed<0><<<ghalf1 * 5, 512, 0, stream>>>(x, Bp, pq, N, 0,
                                                  ei, deg, row_ptr, slot,
                                                  csr_src, E);

    // ---- scans (only serial CSR cost left)
    scan1<<<NB, 1024, 0, stream>>>(deg, row_ptr, partials, N);
    scan23<<<NB, 1024, 0, stream>>>(row_ptr, partials, N, E, NB);

    // ---- dispatch B: gemm tiles ghalf1..gblocks-1 + ALL csr_fill chunks
    gemm_mixed<1><<<ghalf2 * 5, 512, 0, stream>>>(x, Bp, pq, N, ghalf1,
                                                  ei, deg, row_ptr, slot,
                                                  csr_src, E);

    // ---- layer 1 aggregate + epilogue + layer-2 projection (fused)
    sage1_fused<<<(N + 3) / 4, 256, 0, stream>>>(row_ptr, csr_src, pq, b1l,
                                                 W2l, W2r, r, s, N);

    // ---- layer 2 aggregate + epilogue
    sage2_gather<<<(N * 4 + 255) / 256, 256, 0, stream>>>(row_ptr, csr_src, r, s, b2l, out, N);
}